// Round 4
// baseline (772.127 us; speedup 1.0000x reference)
//
#include <hip/hip_runtime.h>

typedef unsigned short u16;
typedef unsigned int u32;
typedef float f32x4 __attribute__((ext_vector_type(4)));
typedef __bf16 bf16x8 __attribute__((ext_vector_type(8)));

#define F 256
#define T_OUT 8
#define N_MONO 150000
#define N_CLEAV 100000
#define N_FRAG 80000
#define N_FRAG_PAD 80128     // 313 * 256
#define N_OUT 40000
#define M_CLEAV_PAD 100352   // 448 * 224 == 392 * 256

static __device__ __forceinline__ u16 f2bf(float f) {
  u32 u = __float_as_uint(f);
  u32 r = (u + 0x7FFFu + ((u >> 16) & 1u)) >> 16;
  return (u16)r;
}
static __device__ __forceinline__ float bf2f(u16 b) {
  return __uint_as_float(((u32)b) << 16);
}
static __device__ __forceinline__ float sigmoidf(float x) {
  return __frcp_rn(1.0f + __expf(-x));
}
static __device__ __forceinline__ float fast_tanh(float x) {
  return 1.0f - 2.0f * __frcp_rn(__expf(2.0f * x) + 1.0f);
}
static __device__ __forceinline__ void async_copy16(const u16* g, const u16* l) {
  __builtin_amdgcn_global_load_lds(
      (const __attribute__((address_space(1))) u32*)g,
      (__attribute__((address_space(3))) u32*)l,
      16, 0, 0);
}

// ------- K0: weight cast + bias sum  +  feature bf16 + gate logits --------
__global__ __launch_bounds__(256) void feat_prep(
    const float* __restrict__ feat, const float* __restrict__ WgL,
    const float* __restrict__ WgR, u16* __restrict__ featb,
    float* __restrict__ glog,
    const float* __restrict__ Wih, const float* __restrict__ Whh,
    const float* __restrict__ bih, const float* __restrict__ bhh,
    u16* __restrict__ Wihb, u16* __restrict__ Whhb, float* __restrict__ bias) {
  int i = blockIdx.x * 256 + threadIdx.x;
  if (i < 1024 * 512) {
    Wihb[i] = f2bf(Wih[i]);
    if (i < 1024 * 256) Whhb[i] = f2bf(Whh[i]);
    if (i < 1024) bias[i] = bih[i] + bhh[i];
  }
  int wave = threadIdx.x >> 6, lane = threadIdx.x & 63;
  int n = blockIdx.x * 4 + wave;
  if (n >= N_MONO) return;
  float4 x = *(const float4*)(feat + (size_t)n * F + lane * 4);
  u32 lo = (u32)f2bf(x.x) | ((u32)f2bf(x.y) << 16);
  u32 hi = (u32)f2bf(x.z) | ((u32)f2bf(x.w) << 16);
  *(uint2*)(featb + (size_t)n * F + lane * 4) = make_uint2(lo, hi);
  float4 wl = *(const float4*)(WgL + lane * 4);
  float4 wr = *(const float4*)(WgR + lane * 4);
  float pl = x.x * wl.x + x.y * wl.y + x.z * wl.z + x.w * wl.w;
  float pr = x.x * wr.x + x.y * wr.y + x.z * wr.z + x.w * wr.w;
#pragma unroll
  for (int off = 32; off; off >>= 1) {
    pl += __shfl_xor(pl, off);
    pr += __shfl_xor(pr, off);
  }
  if (lane == 0) {
    glog[n * 2] = pl;
    glog[n * 2 + 1] = pr;
  }
}

// ---------------- K1: attention pulls -> cleav [N_CLEAV, 512] bf16 --------
__global__ __launch_bounds__(256) void attn_pull2(
    const u16* __restrict__ featb, const float* __restrict__ glog,
    const int* __restrict__ lostS, const int* __restrict__ retS,
    u16* __restrict__ cleav) {
  int wave = threadIdx.x >> 6, lane = threadIdx.x & 63;
  int n = blockIdx.x * 4 + wave;
  if (n >= N_CLEAV) return;
#pragma unroll
  for (int sg = 0; sg < 2; ++sg) {
    const int* src = sg ? retS : lostS;
    int4 ridx = *(const int4*)(src + n * 4);
    int r[4] = {ridx.x, ridx.y, ridx.z, ridx.w};
    ushort4 x4[4];
    float lg[4];
#pragma unroll
    for (int d = 0; d < 4; ++d) {
      x4[d] = *(const ushort4*)(featb + (size_t)r[d] * F + lane * 4);
      lg[d] = glog[r[d] * 2 + sg];
    }
    float mx = fmaxf(fmaxf(lg[0], lg[1]), fmaxf(lg[2], lg[3]));
    float e0 = __expf(lg[0] - mx), e1 = __expf(lg[1] - mx);
    float e2 = __expf(lg[2] - mx), e3 = __expf(lg[3] - mx);
    float inv = __frcp_rn(e0 + e1 + e2 + e3);
    float a[4] = {e0 * inv, e1 * inv, e2 * inv, e3 * inv};
    float acc[4] = {0.f, 0.f, 0.f, 0.f};
#pragma unroll
    for (int d = 0; d < 4; ++d) {
      const u16* xp = (const u16*)&x4[d];
#pragma unroll
      for (int k = 0; k < 4; k++) acc[k] += a[d] * bf2f(xp[k]);
    }
    u32 lo = (u32)f2bf(acc[0]) | ((u32)f2bf(acc[1]) << 16);
    u32 hi = (u32)f2bf(acc[2]) | ((u32)f2bf(acc[3]) << 16);
    *(uint2*)(cleav + (size_t)n * 512 + sg * 256 + lane * 4) = make_uint2(lo, hi);
  }
}

// ---------------- GEMM: 4-phase double-buffered MFMA (see round 2/3) ------
// EPI==0 (GEMM-1): C = acc + bias[n], plain layout.
// EPI==1 (GEMM-2): fused LSTM step-2.  Column remap n -> Whh row
//   gate(n)*256 + nstrip*64 + h(n), gate=(n>>4)&3, h=(n>>6)*16+(n&15),
//   so each lane holds all 4 gates (j=0..3) of hidden unit
//   hg = nstrip*64 + wn4*16 + l16.  Epilogue gathers P[j1[m]] + c1, computes
//   c2/h2, writes h2 panels [4][N_FRAG_PAD][64] bf16 and p2 partials
//   [N_FRAG_PAD][16] f32 (block-owned slots, no atomics).  C not written.
template <int EPI, int K, int BM>
__global__ __launch_bounds__(512, 2) void gemm256(
    const u16* __restrict__ A, const u16* __restrict__ Bw,
    u16* __restrict__ C, const float* __restrict__ bias,
    const int* __restrict__ join, const u16* __restrict__ P,
    const u16* __restrict__ c1, const float* __restrict__ Wg,
    u16* __restrict__ h2s, float* __restrict__ p2p,
    int nper, int mstrips_valid) {
  constexpr int AREG = BM * 64;          // u16 units
  constexpr int BSZ = AREG + 16384;
  constexpr int WMH = BM / 2;            // per-M-wave rows
  constexpr int IB = BM / 32;            // per-wave 16-row blocks (7 or 8)
  constexpr int IB_HI = IB - 4;
  __shared__ u16 sh[2][BSZ];
  const int flat = blockIdx.x;
  const int xcd = flat & 7;
  const int w = flat >> 3;
  const int mstrip = xcd * nper + (w >> 2);
  const int nstrip = w & 3;
  if (mstrip >= mstrips_valid) return;
  const int m0 = mstrip * BM;
  const int n0 = nstrip * 256;

  const int tid = threadIdx.x;
  const int lane = tid & 63;
  const int wave = tid >> 6;
  const int quad = lane >> 4;
  const int l16 = lane & 15;
  const int s7 = l16 & 7;
  const int wm2 = wave >> 2;
  const int wn4 = wave & 3;

  const int arow = (wm2 * WMH + l16) * 64;
  const int brow = AREG + (wn4 * 64 + l16) * 64;
  const int coff0 = (quad ^ s7) * 8;
  const int coff1 = ((4 + quad) ^ s7) * 8;

  int sr[4], sw[4], dwv[4], bsrc[4];
#pragma unroll
  for (int r = 0; r < 4; r++) {
    int c = r * 512 + tid;
    int row = c >> 3;
    sr[r] = row;
    sw[r] = ((c & 7) ^ (row & 7)) * 8;
    dwv[r] = (r * 512 + (tid & ~63)) * 8;
    // B source row: identity for EPI==0; gate-interleave remap for EPI==1
    bsrc[r] = (EPI == 1)
        ? ((row >> 4) & 3) * 256 + nstrip * 64 + ((row >> 6) << 4) + (row & 15)
        : n0 + row;
  }
  const u16* Abase = A + (size_t)m0 * K;

  auto stageA = [&](int buf, int kt, int h) {
#pragma unroll
    for (int rr = 0; rr < 2; rr++) {
      int r = 2 * h + rr;
      if (r * 512 + tid < BM * 8)
        async_copy16(Abase + (size_t)sr[r] * K + kt * 64 + sw[r], &sh[buf][dwv[r]]);
    }
  };
  auto stageB = [&](int buf, int kt, int h) {
#pragma unroll
    for (int rr = 0; rr < 2; rr++) {
      int r = 2 * h + rr;
      async_copy16(Bw + (size_t)bsrc[r] * K + kt * 64 + sw[r], &sh[buf][AREG + dwv[r]]);
    }
  };

  f32x4 acc[IB][4];
#pragma unroll
  for (int i = 0; i < IB; i++)
#pragma unroll
    for (int j = 0; j < 4; j++) acc[i][j] = (f32x4){0.f, 0.f, 0.f, 0.f};

  constexpr int nK = K / 64;
  stageA(0, 0, 0); stageA(0, 0, 1); stageB(0, 0, 0); stageB(0, 0, 1);
  if (nK > 1) { stageB(1, 1, 0); stageB(1, 1, 1); }
  __builtin_amdgcn_s_waitcnt(0xF74);
  __builtin_amdgcn_s_barrier();

  bf16x8 a[4][2], b0[2][2], b1[2][2];
#pragma unroll
  for (int t = 0; t < nK; ++t) {
    const int bsel = t & 1;
    const u16* S = &sh[bsel][0];

    // ---- phase 1
#pragma unroll
    for (int i = 0; i < 4; i++) {
      a[i][0] = *(const bf16x8*)&S[arow + i * 1024 + coff0];
      a[i][1] = *(const bf16x8*)&S[arow + i * 1024 + coff1];
    }
#pragma unroll
    for (int j = 0; j < 2; j++) {
      b0[j][0] = *(const bf16x8*)&S[brow + j * 1024 + coff0];
      b0[j][1] = *(const bf16x8*)&S[brow + j * 1024 + coff1];
    }
    if (t + 1 < nK) stageA(bsel ^ 1, t + 1, 0);
    __builtin_amdgcn_s_waitcnt(0xC87F);
    __builtin_amdgcn_s_barrier();
    __builtin_amdgcn_s_waitcnt(0xC07F);
    __builtin_amdgcn_sched_barrier(0);
    __builtin_amdgcn_s_setprio(1);
#pragma unroll
    for (int i = 0; i < 4; i++)
#pragma unroll
      for (int j = 0; j < 2; j++) {
        acc[i][j] = __builtin_amdgcn_mfma_f32_16x16x32_bf16(a[i][0], b0[j][0], acc[i][j], 0, 0, 0);
        acc[i][j] = __builtin_amdgcn_mfma_f32_16x16x32_bf16(a[i][1], b0[j][1], acc[i][j], 0, 0, 0);
      }
    __builtin_amdgcn_s_setprio(0);
    __builtin_amdgcn_s_barrier();

    // ---- phase 2
#pragma unroll
    for (int j = 0; j < 2; j++) {
      b1[j][0] = *(const bf16x8*)&S[brow + (2 + j) * 1024 + coff0];
      b1[j][1] = *(const bf16x8*)&S[brow + (2 + j) * 1024 + coff1];
    }
    if (t + 1 < nK) stageA(bsel ^ 1, t + 1, 1);
    __builtin_amdgcn_s_barrier();
    __builtin_amdgcn_s_waitcnt(0xC07F);
    __builtin_amdgcn_sched_barrier(0);
    __builtin_amdgcn_s_setprio(1);
#pragma unroll
    for (int i = 0; i < 4; i++)
#pragma unroll
      for (int j = 0; j < 2; j++) {
        acc[i][2 + j] = __builtin_amdgcn_mfma_f32_16x16x32_bf16(a[i][0], b1[j][0], acc[i][2 + j], 0, 0, 0);
        acc[i][2 + j] = __builtin_amdgcn_mfma_f32_16x16x32_bf16(a[i][1], b1[j][1], acc[i][2 + j], 0, 0, 0);
      }
    __builtin_amdgcn_s_setprio(0);
    __builtin_amdgcn_s_barrier();

    // ---- phase 3
#pragma unroll
    for (int i = 0; i < IB_HI; i++) {
      a[i][0] = *(const bf16x8*)&S[arow + (4 + i) * 1024 + coff0];
      a[i][1] = *(const bf16x8*)&S[arow + (4 + i) * 1024 + coff1];
    }
    if (t + 2 < nK) stageB(bsel, t + 2, 0);
    __builtin_amdgcn_s_barrier();
    __builtin_amdgcn_s_waitcnt(0xC07F);
    __builtin_amdgcn_sched_barrier(0);
    __builtin_amdgcn_s_setprio(1);
#pragma unroll
    for (int i = 0; i < IB_HI; i++)
#pragma unroll
      for (int j = 0; j < 2; j++) {
        acc[4 + i][j] = __builtin_amdgcn_mfma_f32_16x16x32_bf16(a[i][0], b0[j][0], acc[4 + i][j], 0, 0, 0);
        acc[4 + i][j] = __builtin_amdgcn_mfma_f32_16x16x32_bf16(a[i][1], b0[j][1], acc[4 + i][j], 0, 0, 0);
      }
    __builtin_amdgcn_s_setprio(0);
    __builtin_amdgcn_s_barrier();

    // ---- phase 4
    if (t + 2 < nK) stageB(bsel, t + 2, 1);
    __builtin_amdgcn_s_barrier();
    __builtin_amdgcn_s_setprio(1);
#pragma unroll
    for (int i = 0; i < IB_HI; i++)
#pragma unroll
      for (int j = 0; j < 2; j++) {
        acc[4 + i][2 + j] = __builtin_amdgcn_mfma_f32_16x16x32_bf16(a[i][0], b1[j][0], acc[4 + i][2 + j], 0, 0, 0);
        acc[4 + i][2 + j] = __builtin_amdgcn_mfma_f32_16x16x32_bf16(a[i][1], b1[j][1], acc[4 + i][2 + j], 0, 0, 0);
      }
    __builtin_amdgcn_s_setprio(0);
    if (t + 2 < nK) __builtin_amdgcn_s_waitcnt(0xF74);
    else            __builtin_amdgcn_s_waitcnt(0xF70);
    __builtin_amdgcn_s_barrier();
  }

  if constexpr (EPI == 0) {
    float badd[4];
#pragma unroll
    for (int j = 0; j < 4; j++)
      badd[j] = bias[n0 + wn4 * 64 + j * 16 + l16];
#pragma unroll
    for (int i = 0; i < IB; i++) {
      const int mrow = m0 + wm2 * WMH + i * 16 + quad * 4;
#pragma unroll
      for (int j = 0; j < 4; j++) {
        const int n = n0 + wn4 * 64 + j * 16 + l16;
#pragma unroll
        for (int r = 0; r < 4; r++)
          C[(size_t)(mrow + r) * 1024 + n] = f2bf(acc[i][j][r] + badd[j]);
      }
    }
  } else {
    // fused LSTM step-2: lane owns hidden unit hg (all 4 gates in j=0..3)
    const int hg = nstrip * 64 + wn4 * 16 + l16;
    const float wgv = Wg[hg];
#pragma unroll
    for (int i = 0; i < IB; i++) {
#pragma unroll
      for (int r = 0; r < 4; r++) {
        const int m = m0 + wm2 * WMH + i * 16 + quad * 4 + r;
        const int j1 = (m < N_FRAG) ? join[2 * m + 1] : 0;
        const u16* prow = P + (size_t)j1 * 1024 + hg;
        float gi = acc[i][0][r] + bf2f(prow[0]);
        float gf = acc[i][1][r] + bf2f(prow[256]);
        float gg = acc[i][2][r] + bf2f(prow[512]);
        float go = acc[i][3][r] + bf2f(prow[768]);
        float c1v = bf2f(c1[(size_t)m * 256 + hg]);
        float c2 = sigmoidf(gf) * c1v + sigmoidf(gi) * fast_tanh(gg);
        float h2 = sigmoidf(go) * fast_tanh(c2);
        float p = h2 * wgv;
        p += __shfl_xor(p, 1); p += __shfl_xor(p, 2);
        p += __shfl_xor(p, 4); p += __shfl_xor(p, 8);
        if (l16 == 0) p2p[(size_t)m * 16 + nstrip * 4 + wn4] = p;
        h2s[((size_t)nstrip * N_FRAG_PAD + m) * 64 + wn4 * 16 + l16] = f2bf(h2);
      }
    }
  }
}

// ---------------- K3: LSTM step 1 + p1 logit, wave-per-fragment -----------
__global__ __launch_bounds__(256) void lstm_step1(
    const u16* __restrict__ P, const int* __restrict__ join,
    const float* __restrict__ Wg, u16* __restrict__ h1,
    u16* __restrict__ c1, float* __restrict__ p1) {
  int wave = threadIdx.x >> 6, lane = threadIdx.x & 63;
  int m = blockIdx.x * 4 + wave;
  if (m >= N_FRAG) return;
  int j0 = join[2 * m];
  const u16* row = P + (size_t)j0 * 1024 + lane * 4;
  ushort4 iv = *(const ushort4*)(row);
  ushort4 gv = *(const ushort4*)(row + 512);
  ushort4 ov = *(const ushort4*)(row + 768);
  float4 wg = *(const float4*)(Wg + lane * 4);
  const u16* ivp = (const u16*)&iv;
  const u16* gvp = (const u16*)&gv;
  const u16* ovp = (const u16*)&ov;
  const float* wgp = (const float*)&wg;
  ushort4 h4, c4;
  u16* h4p = (u16*)&h4;
  u16* c4p = (u16*)&c4;
  float pl = 0.f;
#pragma unroll
  for (int k = 0; k < 4; k++) {
    float c = sigmoidf(bf2f(ivp[k])) * fast_tanh(bf2f(gvp[k]));
    float hv = sigmoidf(bf2f(ovp[k])) * fast_tanh(c);
    h4p[k] = f2bf(hv);
    c4p[k] = f2bf(c);
    pl += bf2f(h4p[k]) * wgp[k];   // match final-kernel's bf16 h1 read
  }
#pragma unroll
  for (int off = 32; off; off >>= 1) pl += __shfl_xor(pl, off);
  *(ushort4*)(h1 + (size_t)m * 256 + lane * 4) = h4;
  *(ushort4*)(c1 + (size_t)m * 256 + lane * 4) = c4;
  if (lane == 0) p1[m] = pl;
}

// ------- K5: attention over {h1,h2} + output head (light) -----------------
__global__ __launch_bounds__(256) void lstm_attn_out(
    const u16* __restrict__ h1, const u16* __restrict__ h2s,
    const float* __restrict__ p1, const float* __restrict__ p2p,
    const float* __restrict__ Wout, const float* __restrict__ bout,
    float* __restrict__ frag_out) {
  int wave = threadIdx.x >> 6, lane = threadIdx.x & 63;
  int m = blockIdx.x * 4 + wave;
  if (m >= N_FRAG) return;
  // p2 = sum of 16 partials: lanes (lane&3) each grab a float4, tree-sum
  float4 q = *(const float4*)(p2p + (size_t)m * 16 + (lane & 3) * 4);
  float p2 = q.x + q.y + q.z + q.w;
  p2 += __shfl_xor(p2, 1);
  p2 += __shfl_xor(p2, 2);
  float p1v = p1[m];
  float mx = fmaxf(p1v, p2);
  float e1 = __expf(p1v - mx), e2 = __expf(p2 - mx);
  float inv = __frcp_rn(e1 + e2);
  float a1 = e1 * inv, a2 = e2 * inv;

  ushort4 h1v = *(const ushort4*)(h1 + (size_t)m * 256 + lane * 4);
  ushort4 h2v = *(const ushort4*)(h2s + ((size_t)(lane >> 4) * N_FRAG_PAD + m) * 64 + (lane & 15) * 4);
  const u16* h1p = (const u16*)&h1v;
  const u16* h2p = (const u16*)&h2v;

  float acc[8];
#pragma unroll
  for (int t = 0; t < 8; t++) acc[t] = 0.f;
#pragma unroll
  for (int k = 0; k < 4; k++) {
    float frag = a1 * bf2f(h1p[k]) + a2 * bf2f(h2p[k]);
    int h = lane * 4 + k;
    float4 w0 = *(const float4*)(Wout + h * 8);
    float4 w1 = *(const float4*)(Wout + h * 8 + 4);
    acc[0] += frag * w0.x; acc[1] += frag * w0.y;
    acc[2] += frag * w0.z; acc[3] += frag * w0.w;
    acc[4] += frag * w1.x; acc[5] += frag * w1.y;
    acc[6] += frag * w1.z; acc[7] += frag * w1.w;
  }
#pragma unroll
  for (int off = 32; off; off >>= 1)
#pragma unroll
    for (int t = 0; t < 8; t++) acc[t] += __shfl_xor(acc[t], off);
  if (lane == 0) {
    float4 o0, o1;
    o0.x = fmaxf(acc[0] + bout[0], 0.f);
    o0.y = fmaxf(acc[1] + bout[1], 0.f);
    o0.z = fmaxf(acc[2] + bout[2], 0.f);
    o0.w = fmaxf(acc[3] + bout[3], 0.f);
    o1.x = fmaxf(acc[4] + bout[4], 0.f);
    o1.y = fmaxf(acc[5] + bout[5], 0.f);
    o1.z = fmaxf(acc[6] + bout[6], 0.f);
    o1.w = fmaxf(acc[7] + bout[7], 0.f);
    *(float4*)(frag_out + (size_t)m * 8) = o0;
    *(float4*)(frag_out + (size_t)m * 8 + 4) = o1;
  }
}

// ---------------- K6: combine scatter-sum ---------------------------------
__global__ __launch_bounds__(256) void scatter_sum(
    const float* __restrict__ frag_out, const int* __restrict__ comb,
    float* __restrict__ out) {
  int tid = blockIdx.x * 256 + threadIdx.x;
  if (tid >= N_OUT * 8) return;
  int n = tid >> 3, t = tid & 7;
  float s = 0.f;
#pragma unroll
  for (int d = 0; d < 4; d++) {
    int f = comb[n * 4 + d];
    s += frag_out[(size_t)f * 8 + t];
  }
  out[tid] = s;
}

extern "C" void kernel_launch(void* const* d_in, const int* in_sizes, int n_in,
                              void* d_out, int out_size, void* d_ws, size_t ws_size,
                              hipStream_t stream) {
  const float* feature = (const float*)d_in[0];
  const float* WgL = (const float*)d_in[1];
  const float* WgR = (const float*)d_in[2];
  const float* Wih = (const float*)d_in[3];
  const float* Whh = (const float*)d_in[4];
  const float* bih = (const float*)d_in[5];
  const float* bhh = (const float*)d_in[6];
  const float* Wgf = (const float*)d_in[7];
  const float* Wout = (const float*)d_in[8];
  const float* bout = (const float*)d_in[9];
  const int* lostS = (const int*)d_in[10];
  const int* retS = (const int*)d_in[11];
  const int* joinS = (const int*)d_in[12];
  const int* combS = (const int*)d_in[13];
  float* out = (float*)d_out;

  char* ws = (char*)d_ws;
  size_t off = 0;
  auto alloc = [&](size_t bytes) -> char* {
    char* p = ws + off;
    off = (off + bytes + 255) & ~(size_t)255;
    return p;
  };
  u16* Wihb = (u16*)alloc((size_t)1024 * 512 * 2);
  u16* Whhb = (u16*)alloc((size_t)1024 * 256 * 2);
  float* bias = (float*)alloc(1024 * 4);
  u16* P = (u16*)alloc((size_t)M_CLEAV_PAD * 1024 * 2);
  u16* h1 = (u16*)alloc((size_t)N_FRAG_PAD * 256 * 2);
  u16* c1 = (u16*)alloc((size_t)N_FRAG_PAD * 256 * 2);
  u16* h2s = (u16*)alloc((size_t)4 * N_FRAG_PAD * 64 * 2);
  float* p2p = (float*)alloc((size_t)N_FRAG_PAD * 16 * 4);
  float* p1 = (float*)alloc((size_t)N_FRAG_PAD * 4);
  float* frag_out = (float*)alloc((size_t)N_FRAG * 8 * 4);
  u16* cleav = (u16*)alloc((size_t)M_CLEAV_PAD * 1024 * 2);
  // featb (76.8 MB) + glog (1.2 MB) alias the P region: dead once
  // attn_pull2 completes, before GEMM-1 writes P (stream-ordered).
  u16* featb = P;
  float* glog = (float*)(P + (size_t)N_MONO * F);

  feat_prep<<<(N_MONO + 3) / 4, 256, 0, stream>>>(
      feature, WgL, WgR, featb, glog, Wih, Whh, bih, bhh, Wihb, Whhb, bias);
  attn_pull2<<<N_CLEAV / 4, 256, 0, stream>>>(featb, glog, lostS, retS, cleav);
  // GEMM-1: M=100352 = 448*224 strips, 56 per XCD, 1792 blocks = 7/CU exact
  gemm256<0, 512, 224><<<1792, 512, 0, stream>>>(
      cleav, Wihb, P, bias, nullptr, nullptr, nullptr, nullptr, nullptr, nullptr,
      56, 448);
  lstm_step1<<<N_FRAG / 4, 256, 0, stream>>>(P, joinS, Wgf, h1, c1, p1);
  // GEMM-2 (fused LSTM step-2): M=80128 -> 313 strips of 256, 320 virtual
  // (40/XCD), tail early-exits; 1280 blocks = 5/CU.
  gemm256<1, 256, 256><<<1280, 512, 0, stream>>>(
      h1, Whhb, nullptr, nullptr, joinS, P, c1, Wgf, h2s, p2p,
      40, 313);
  lstm_attn_out<<<N_FRAG / 4, 256, 0, stream>>>(
      h1, h2s, p1, p2p, Wout, bout, frag_out);
  scatter_sum<<<(N_OUT * 8 + 255) / 256, 256, 0, stream>>>(frag_out, combS, out);
}

// Round 5
// 729.350 us; speedup vs baseline: 1.0586x; 1.0586x over previous
//
#include <hip/hip_runtime.h>

typedef unsigned short u16;
typedef unsigned int u32;
typedef float f32x4 __attribute__((ext_vector_type(4)));
typedef __bf16 bf16x8 __attribute__((ext_vector_type(8)));

#define F 256
#define T_OUT 8
#define N_MONO 150000
#define N_CLEAV 100000
#define N_FRAG 80000
#define N_FRAG_PAD 80128     // 313 * 256
#define N_OUT 40000

static __device__ __forceinline__ u16 f2bf(float f) {
  u32 u = __float_as_uint(f);
  u32 r = (u + 0x7FFFu + ((u >> 16) & 1u)) >> 16;
  return (u16)r;
}
static __device__ __forceinline__ float bf2f(u16 b) {
  return __uint_as_float(((u32)b) << 16);
}
static __device__ __forceinline__ float sigmoidf(float x) {
  return __frcp_rn(1.0f + __expf(-x));
}
static __device__ __forceinline__ float fast_tanh(float x) {
  return 1.0f - 2.0f * __frcp_rn(__expf(2.0f * x) + 1.0f);
}
static __device__ __forceinline__ void async_copy16(const u16* g, const u16* l) {
  __builtin_amdgcn_global_load_lds(
      (const __attribute__((address_space(1))) u32*)g,
      (__attribute__((address_space(3))) u32*)l,
      16, 0, 0);
}

// ------- K0: weight cast + bias sum  +  feature bf16 + gate logits --------
__global__ __launch_bounds__(256) void feat_prep(
    const float* __restrict__ feat, const float* __restrict__ WgL,
    const float* __restrict__ WgR, u16* __restrict__ featb,
    float* __restrict__ glog,
    const float* __restrict__ Wih, const float* __restrict__ Whh,
    const float* __restrict__ bih, const float* __restrict__ bhh,
    u16* __restrict__ Wihb, u16* __restrict__ Whhb, float* __restrict__ bias) {
  int i = blockIdx.x * 256 + threadIdx.x;
  if (i < 1024 * 512) {
    Wihb[i] = f2bf(Wih[i]);
    if (i < 1024 * 256) Whhb[i] = f2bf(Whh[i]);
    if (i < 1024) bias[i] = bih[i] + bhh[i];
  }
  int wave = threadIdx.x >> 6, lane = threadIdx.x & 63;
  int n = blockIdx.x * 4 + wave;
  if (n >= N_MONO) return;
  float4 x = *(const float4*)(feat + (size_t)n * F + lane * 4);
  u32 lo = (u32)f2bf(x.x) | ((u32)f2bf(x.y) << 16);
  u32 hi = (u32)f2bf(x.z) | ((u32)f2bf(x.w) << 16);
  *(uint2*)(featb + (size_t)n * F + lane * 4) = make_uint2(lo, hi);
  float4 wl = *(const float4*)(WgL + lane * 4);
  float4 wr = *(const float4*)(WgR + lane * 4);
  float pl = x.x * wl.x + x.y * wl.y + x.z * wl.z + x.w * wl.w;
  float pr = x.x * wr.x + x.y * wr.y + x.z * wr.z + x.w * wr.w;
#pragma unroll
  for (int off = 32; off; off >>= 1) {
    pl += __shfl_xor(pl, off);
    pr += __shfl_xor(pr, off);
  }
  if (lane == 0) {
    glog[n * 2] = pl;
    glog[n * 2 + 1] = pr;
  }
}

// ---------------- K1: attention pulls -> cleav [N_CLEAV, 512] bf16 --------
__global__ __launch_bounds__(256) void attn_pull2(
    const u16* __restrict__ featb, const float* __restrict__ glog,
    const int* __restrict__ lostS, const int* __restrict__ retS,
    u16* __restrict__ cleav) {
  int wave = threadIdx.x >> 6, lane = threadIdx.x & 63;
  int n = blockIdx.x * 4 + wave;
  if (n >= N_CLEAV) return;
#pragma unroll
  for (int sg = 0; sg < 2; ++sg) {
    const int* src = sg ? retS : lostS;
    int4 ridx = *(const int4*)(src + n * 4);
    int r[4] = {ridx.x, ridx.y, ridx.z, ridx.w};
    ushort4 x4[4];
    float lg[4];
#pragma unroll
    for (int d = 0; d < 4; ++d) {
      x4[d] = *(const ushort4*)(featb + (size_t)r[d] * F + lane * 4);
      lg[d] = glog[r[d] * 2 + sg];
    }
    float mx = fmaxf(fmaxf(lg[0], lg[1]), fmaxf(lg[2], lg[3]));
    float e0 = __expf(lg[0] - mx), e1 = __expf(lg[1] - mx);
    float e2 = __expf(lg[2] - mx), e3 = __expf(lg[3] - mx);
    float inv = __frcp_rn(e0 + e1 + e2 + e3);
    float a[4] = {e0 * inv, e1 * inv, e2 * inv, e3 * inv};
    float acc[4] = {0.f, 0.f, 0.f, 0.f};
#pragma unroll
    for (int d = 0; d < 4; ++d) {
      const u16* xp = (const u16*)&x4[d];
#pragma unroll
      for (int k = 0; k < 4; k++) acc[k] += a[d] * bf2f(xp[k]);
    }
    u32 lo = (u32)f2bf(acc[0]) | ((u32)f2bf(acc[1]) << 16);
    u32 hi = (u32)f2bf(acc[2]) | ((u32)f2bf(acc[3]) << 16);
    *(uint2*)(cleav + (size_t)n * 512 + sg * 256 + lane * 4) = make_uint2(lo, hi);
  }
}

// ------- Fragment-space gate GEMM with fused LSTM nonlinearity -----------
// STEP==0 (S1): gates1[m] = cleav[j0[m]] @ Wih^T + b  (K=512).
//   Epilogue (c0=0): c1 = sig(i)*tanh(g); h1 = sig(o)*tanh(c1);
//   writes h1, c1 [m][256] bf16 + p1 partials [m][16] f32.  Gather-free.
// STEP==1 (S2): gates2[m] = [cleav[j1[m]], h1[m]] @ [Wih;Whh]^T + b (K=768).
//   Epilogue: c2 = sig(f)*c1[m] + sig(i)*tanh(g); h2 = sig(o)*tanh(c2);
//   writes h2 panels [4][N_FRAG_PAD][64] bf16 + p2 partials.  c1[m] is
//   m-indexed (independent addresses, no dependent gather chain).
// A-staging is GATHERED: global_load_lds source is per-lane; row indices
// j{0,1}[m] preloaded into regs once per block.  B uses the gate-interleave
// remap (row = gate*256 + nstrip*64 + unit) so each lane's 4 j-quadrants
// hold the 4 gates of one hidden unit hg = nstrip*64 + wn4*16 + l16.
// Main loop = verified 4-phase double-buffered schedule (rounds 2-3).
template <int STEP, int K>
__global__ __launch_bounds__(512, 2) void gemm_frag(
    const u16* __restrict__ cleavA, const u16* __restrict__ h1A,
    const u16* __restrict__ Wihb, const u16* __restrict__ Whhb,
    const int* __restrict__ join, const float* __restrict__ bias,
    const u16* __restrict__ c1in, const float* __restrict__ Wg,
    u16* __restrict__ h1out, u16* __restrict__ c1out, u16* __restrict__ h2s,
    float* __restrict__ pp,
    int nper, int mstrips_valid) {
  constexpr int AREG = 256 * 64;         // u16 units
  constexpr int BSZ = AREG + 16384;
  __shared__ u16 sh[2][BSZ];
  const int flat = blockIdx.x;
  const int xcd = flat & 7;
  const int w = flat >> 3;
  const int mstrip = xcd * nper + (w >> 2);
  const int nstrip = w & 3;
  if (mstrip >= mstrips_valid) return;
  const int m0 = mstrip * 256;

  const int tid = threadIdx.x;
  const int lane = tid & 63;
  const int wave = tid >> 6;
  const int quad = lane >> 4;
  const int l16 = lane & 15;
  const int s7 = l16 & 7;
  const int wm2 = wave >> 2;
  const int wn4 = wave & 3;

  const int arow = (wm2 * 128 + l16) * 64;
  const int brow = AREG + (wn4 * 64 + l16) * 64;
  const int coff0 = (quad ^ s7) * 8;
  const int coff1 = ((4 + quad) ^ s7) * 8;

  // staging rounds: chunk c = r*512 + tid; row = c>>3, phys chunk c&7
  int sr[4], sw[4], dwv[4], bsrc[4], jidx[4];
#pragma unroll
  for (int r = 0; r < 4; r++) {
    int c = r * 512 + tid;
    int row = c >> 3;
    sr[r] = row;
    sw[r] = ((c & 7) ^ (row & 7)) * 8;
    dwv[r] = (r * 512 + (tid & ~63)) * 8;
    bsrc[r] = ((row >> 4) & 3) * 256 + nstrip * 64 + ((row >> 6) << 4) + (row & 15);
    int m = m0 + row;
    int mi = m < N_FRAG ? m : N_FRAG - 1;
    jidx[r] = join[2 * mi + STEP];
  }

  auto stageA = [&](int buf, int kt, int h) {
#pragma unroll
    for (int rr = 0; rr < 2; rr++) {
      int r = 2 * h + rr;
      const u16* src;
      if (STEP == 1 && kt >= 8)
        src = h1A + (size_t)(m0 + sr[r]) * 256 + (kt - 8) * 64 + sw[r];
      else
        src = cleavA + (size_t)jidx[r] * 512 + kt * 64 + sw[r];
      async_copy16(src, &sh[buf][dwv[r]]);
    }
  };
  auto stageB = [&](int buf, int kt, int h) {
#pragma unroll
    for (int rr = 0; rr < 2; rr++) {
      int r = 2 * h + rr;
      const u16* src;
      if (STEP == 1 && kt >= 8)
        src = Whhb + (size_t)bsrc[r] * 256 + (kt - 8) * 64 + sw[r];
      else
        src = Wihb + (size_t)bsrc[r] * 512 + kt * 64 + sw[r];
      async_copy16(src, &sh[buf][AREG + dwv[r]]);
    }
  };

  f32x4 acc[8][4];
#pragma unroll
  for (int i = 0; i < 8; i++)
#pragma unroll
    for (int j = 0; j < 4; j++) acc[i][j] = (f32x4){0.f, 0.f, 0.f, 0.f};

  constexpr int nK = K / 64;
  stageA(0, 0, 0); stageA(0, 0, 1); stageB(0, 0, 0); stageB(0, 0, 1);
  if (nK > 1) { stageB(1, 1, 0); stageB(1, 1, 1); }
  __builtin_amdgcn_s_waitcnt(0xF74);  // vmcnt(4): tile0 landed, B(1) in flight
  __builtin_amdgcn_s_barrier();

  bf16x8 a[4][2], b0[2][2], b1[2][2];
#pragma unroll
  for (int t = 0; t < nK; ++t) {
    const int bsel = t & 1;
    const u16* S = &sh[bsel][0];

    // ---- phase 1: i 0-3, j 0-1; stage A(t+1) half0.
#pragma unroll
    for (int i = 0; i < 4; i++) {
      a[i][0] = *(const bf16x8*)&S[arow + i * 1024 + coff0];
      a[i][1] = *(const bf16x8*)&S[arow + i * 1024 + coff1];
    }
#pragma unroll
    for (int j = 0; j < 2; j++) {
      b0[j][0] = *(const bf16x8*)&S[brow + j * 1024 + coff0];
      b0[j][1] = *(const bf16x8*)&S[brow + j * 1024 + coff1];
    }
    if (t + 1 < nK) stageA(bsel ^ 1, t + 1, 0);
    __builtin_amdgcn_s_waitcnt(0xC87F);  // lgkmcnt(8) pre-barrier
    __builtin_amdgcn_s_barrier();
    __builtin_amdgcn_s_waitcnt(0xC07F);  // lgkmcnt(0)
    __builtin_amdgcn_sched_barrier(0);
    __builtin_amdgcn_s_setprio(1);
#pragma unroll
    for (int i = 0; i < 4; i++)
#pragma unroll
      for (int j = 0; j < 2; j++) {
        acc[i][j] = __builtin_amdgcn_mfma_f32_16x16x32_bf16(a[i][0], b0[j][0], acc[i][j], 0, 0, 0);
        acc[i][j] = __builtin_amdgcn_mfma_f32_16x16x32_bf16(a[i][1], b0[j][1], acc[i][j], 0, 0, 0);
      }
    __builtin_amdgcn_s_setprio(0);
    __builtin_amdgcn_s_barrier();

    // ---- phase 2: i 0-3, j 2-3; stage A(t+1) half1.
#pragma unroll
    for (int j = 0; j < 2; j++) {
      b1[j][0] = *(const bf16x8*)&S[brow + (2 + j) * 1024 + coff0];
      b1[j][1] = *(const bf16x8*)&S[brow + (2 + j) * 1024 + coff1];
    }
    if (t + 1 < nK) stageA(bsel ^ 1, t + 1, 1);
    __builtin_amdgcn_s_barrier();
    __builtin_amdgcn_s_waitcnt(0xC07F);
    __builtin_amdgcn_sched_barrier(0);
    __builtin_amdgcn_s_setprio(1);
#pragma unroll
    for (int i = 0; i < 4; i++)
#pragma unroll
      for (int j = 0; j < 2; j++) {
        acc[i][2 + j] = __builtin_amdgcn_mfma_f32_16x16x32_bf16(a[i][0], b1[j][0], acc[i][2 + j], 0, 0, 0);
        acc[i][2 + j] = __builtin_amdgcn_mfma_f32_16x16x32_bf16(a[i][1], b1[j][1], acc[i][2 + j], 0, 0, 0);
      }
    __builtin_amdgcn_s_setprio(0);
    __builtin_amdgcn_s_barrier();

    // ---- phase 3: i 4-7, j 0-1; stage B(t+2) half0.
#pragma unroll
    for (int i = 0; i < 4; i++) {
      a[i][0] = *(const bf16x8*)&S[arow + (4 + i) * 1024 + coff0];
      a[i][1] = *(const bf16x8*)&S[arow + (4 + i) * 1024 + coff1];
    }
    if (t + 2 < nK) stageB(bsel, t + 2, 0);
    __builtin_amdgcn_s_barrier();
    __builtin_amdgcn_s_waitcnt(0xC07F);
    __builtin_amdgcn_sched_barrier(0);
    __builtin_amdgcn_s_setprio(1);
#pragma unroll
    for (int i = 0; i < 4; i++)
#pragma unroll
      for (int j = 0; j < 2; j++) {
        acc[4 + i][j] = __builtin_amdgcn_mfma_f32_16x16x32_bf16(a[i][0], b0[j][0], acc[4 + i][j], 0, 0, 0);
        acc[4 + i][j] = __builtin_amdgcn_mfma_f32_16x16x32_bf16(a[i][1], b0[j][1], acc[4 + i][j], 0, 0, 0);
      }
    __builtin_amdgcn_s_setprio(0);
    __builtin_amdgcn_s_barrier();

    // ---- phase 4: i 4-7, j 2-3; stage B(t+2) half1; boundary vmcnt.
    if (t + 2 < nK) stageB(bsel, t + 2, 1);
    __builtin_amdgcn_s_barrier();
    __builtin_amdgcn_s_setprio(1);
#pragma unroll
    for (int i = 0; i < 4; i++)
#pragma unroll
      for (int j = 0; j < 2; j++) {
        acc[4 + i][2 + j] = __builtin_amdgcn_mfma_f32_16x16x32_bf16(a[i][0], b1[j][0], acc[4 + i][2 + j], 0, 0, 0);
        acc[4 + i][2 + j] = __builtin_amdgcn_mfma_f32_16x16x32_bf16(a[i][1], b1[j][1], acc[4 + i][2 + j], 0, 0, 0);
      }
    __builtin_amdgcn_s_setprio(0);
    if (t + 2 < nK) __builtin_amdgcn_s_waitcnt(0xF74);  // vmcnt(4)
    else            __builtin_amdgcn_s_waitcnt(0xF70);  // vmcnt(0)
    __builtin_amdgcn_s_barrier();
  }

  // ---- fused LSTM epilogue (gather-free) ----
  const int hg = nstrip * 64 + wn4 * 16 + l16;
  const float bI = bias[hg];
  const float bF = bias[256 + hg];
  const float bG = bias[512 + hg];
  const float bO = bias[768 + hg];
  const float wgv = Wg[hg];
#pragma unroll
  for (int i = 0; i < 8; i++) {
#pragma unroll
    for (int r = 0; r < 4; r++) {
      const int m = m0 + wm2 * 128 + i * 16 + quad * 4 + r;
      float gi = acc[i][0][r] + bI;
      float gg = acc[i][2][r] + bG;
      float go = acc[i][3][r] + bO;
      float hv;
      if (STEP == 0) {
        float cv = sigmoidf(gi) * fast_tanh(gg);
        hv = sigmoidf(go) * fast_tanh(cv);
        h1out[(size_t)m * 256 + hg] = f2bf(hv);
        c1out[(size_t)m * 256 + hg] = f2bf(cv);
      } else {
        float gf = acc[i][1][r] + bF;
        float c1v = bf2f(c1in[(size_t)m * 256 + hg]);
        float cv = sigmoidf(gf) * c1v + sigmoidf(gi) * fast_tanh(gg);
        hv = sigmoidf(go) * fast_tanh(cv);
        h2s[((size_t)nstrip * N_FRAG_PAD + m) * 64 + wn4 * 16 + l16] = f2bf(hv);
      }
      float p = bf2f(f2bf(hv)) * wgv;
      p += __shfl_xor(p, 1); p += __shfl_xor(p, 2);
      p += __shfl_xor(p, 4); p += __shfl_xor(p, 8);
      if (l16 == 0) pp[(size_t)m * 16 + nstrip * 4 + wn4] = p;
    }
  }
}

// ------- K5: attention over {h1,h2} + output head (light) -----------------
__global__ __launch_bounds__(256) void lstm_attn_out(
    const u16* __restrict__ h1, const u16* __restrict__ h2s,
    const float* __restrict__ p1p, const float* __restrict__ p2p,
    const float* __restrict__ Wout, const float* __restrict__ bout,
    float* __restrict__ frag_out) {
  int wave = threadIdx.x >> 6, lane = threadIdx.x & 63;
  int m = blockIdx.x * 4 + wave;
  if (m >= N_FRAG) return;
  float4 q2 = *(const float4*)(p2p + (size_t)m * 16 + (lane & 3) * 4);
  float p2 = q2.x + q2.y + q2.z + q2.w;
  p2 += __shfl_xor(p2, 1);
  p2 += __shfl_xor(p2, 2);
  float4 q1 = *(const float4*)(p1p + (size_t)m * 16 + (lane & 3) * 4);
  float p1 = q1.x + q1.y + q1.z + q1.w;
  p1 += __shfl_xor(p1, 1);
  p1 += __shfl_xor(p1, 2);
  float mx = fmaxf(p1, p2);
  float e1 = __expf(p1 - mx), e2 = __expf(p2 - mx);
  float inv = __frcp_rn(e1 + e2);
  float a1 = e1 * inv, a2 = e2 * inv;

  ushort4 h1v = *(const ushort4*)(h1 + (size_t)m * 256 + lane * 4);
  ushort4 h2v = *(const ushort4*)(h2s + ((size_t)(lane >> 4) * N_FRAG_PAD + m) * 64 + (lane & 15) * 4);
  const u16* h1p = (const u16*)&h1v;
  const u16* h2p = (const u16*)&h2v;

  float acc[8];
#pragma unroll
  for (int t = 0; t < 8; t++) acc[t] = 0.f;
#pragma unroll
  for (int k = 0; k < 4; k++) {
    float frag = a1 * bf2f(h1p[k]) + a2 * bf2f(h2p[k]);
    int h = lane * 4 + k;
    float4 w0 = *(const float4*)(Wout + h * 8);
    float4 w1 = *(const float4*)(Wout + h * 8 + 4);
    acc[0] += frag * w0.x; acc[1] += frag * w0.y;
    acc[2] += frag * w0.z; acc[3] += frag * w0.w;
    acc[4] += frag * w1.x; acc[5] += frag * w1.y;
    acc[6] += frag * w1.z; acc[7] += frag * w1.w;
  }
#pragma unroll
  for (int off = 32; off; off >>= 1)
#pragma unroll
    for (int t = 0; t < 8; t++) acc[t] += __shfl_xor(acc[t], off);
  if (lane == 0) {
    float4 o0, o1;
    o0.x = fmaxf(acc[0] + bout[0], 0.f);
    o0.y = fmaxf(acc[1] + bout[1], 0.f);
    o0.z = fmaxf(acc[2] + bout[2], 0.f);
    o0.w = fmaxf(acc[3] + bout[3], 0.f);
    o1.x = fmaxf(acc[4] + bout[4], 0.f);
    o1.y = fmaxf(acc[5] + bout[5], 0.f);
    o1.z = fmaxf(acc[6] + bout[6], 0.f);
    o1.w = fmaxf(acc[7] + bout[7], 0.f);
    *(float4*)(frag_out + (size_t)m * 8) = o0;
    *(float4*)(frag_out + (size_t)m * 8 + 4) = o1;
  }
}

// ---------------- K6: combine scatter-sum ---------------------------------
__global__ __launch_bounds__(256) void scatter_sum(
    const float* __restrict__ frag_out, const int* __restrict__ comb,
    float* __restrict__ out) {
  int tid = blockIdx.x * 256 + threadIdx.x;
  if (tid >= N_OUT * 8) return;
  int n = tid >> 3, t = tid & 7;
  float s = 0.f;
#pragma unroll
  for (int d = 0; d < 4; d++) {
    int f = comb[n * 4 + d];
    s += frag_out[(size_t)f * 8 + t];
  }
  out[tid] = s;
}

extern "C" void kernel_launch(void* const* d_in, const int* in_sizes, int n_in,
                              void* d_out, int out_size, void* d_ws, size_t ws_size,
                              hipStream_t stream) {
  const float* feature = (const float*)d_in[0];
  const float* WgL = (const float*)d_in[1];
  const float* WgR = (const float*)d_in[2];
  const float* Wih = (const float*)d_in[3];
  const float* Whh = (const float*)d_in[4];
  const float* bih = (const float*)d_in[5];
  const float* bhh = (const float*)d_in[6];
  const float* Wgf = (const float*)d_in[7];
  const float* Wout = (const float*)d_in[8];
  const float* bout = (const float*)d_in[9];
  const int* lostS = (const int*)d_in[10];
  const int* retS = (const int*)d_in[11];
  const int* joinS = (const int*)d_in[12];
  const int* combS = (const int*)d_in[13];
  float* out = (float*)d_out;

  char* ws = (char*)d_ws;
  size_t off = 0;
  auto alloc = [&](size_t bytes) -> char* {
    char* p = ws + off;
    off = (off + bytes + 255) & ~(size_t)255;
    return p;
  };
  u16* Wihb = (u16*)alloc((size_t)1024 * 512 * 2);
  u16* Whhb = (u16*)alloc((size_t)1024 * 256 * 2);
  float* bias = (float*)alloc(1024 * 4);
  u16* featb = (u16*)alloc((size_t)N_MONO * F * 2);
  float* glog = (float*)alloc((size_t)N_MONO * 2 * 4);
  u16* cleav = (u16*)alloc((size_t)N_CLEAV * 512 * 2);
  u16* h1 = (u16*)alloc((size_t)N_FRAG_PAD * 256 * 2);
  u16* c1 = (u16*)alloc((size_t)N_FRAG_PAD * 256 * 2);
  u16* h2s = (u16*)alloc((size_t)4 * N_FRAG_PAD * 64 * 2);
  float* p1p = (float*)alloc((size_t)N_FRAG_PAD * 16 * 4);
  float* p2p = (float*)alloc((size_t)N_FRAG_PAD * 16 * 4);
  float* frag_out = (float*)alloc((size_t)N_FRAG * 8 * 4);

  feat_prep<<<(N_MONO + 3) / 4, 256, 0, stream>>>(
      feature, WgL, WgR, featb, glog, Wih, Whh, bih, bhh, Wihb, Whhb, bias);
  attn_pull2<<<N_CLEAV / 4, 256, 0, stream>>>(featb, glog, lostS, retS, cleav);
  // S1: M=80128 -> 313 strips of 256, 320 virtual (40/XCD), tail early-exits
  gemm_frag<0, 512><<<1280, 512, 0, stream>>>(
      cleav, nullptr, Wihb, Whhb, joinS, bias, nullptr, Wgf,
      h1, c1, nullptr, p1p, 40, 313);
  // S2: K=768 concat [cleav[j1], h1] @ [Wih;Whh]^T, fused step-2 epilogue
  gemm_frag<1, 768><<<1280, 512, 0, stream>>>(
      cleav, h1, Wihb, Whhb, joinS, bias, c1, Wgf,
      nullptr, nullptr, h2s, p2p, 40, 313);
  lstm_attn_out<<<N_FRAG / 4, 256, 0, stream>>>(
      h1, h2s, p1p, p2p, Wout, bout, frag_out);
  scatter_sum<<<(N_OUT * 8 + 255) / 256, 256, 0, stream>>>(frag_out, combS, out);
}

// Round 6
// 701.095 us; speedup vs baseline: 1.1013x; 1.0403x over previous
//
#include <hip/hip_runtime.h>

typedef unsigned short u16;
typedef unsigned int u32;
typedef float f32x4 __attribute__((ext_vector_type(4)));
typedef __bf16 bf16x8 __attribute__((ext_vector_type(8)));

#define F 256
#define T_OUT 8
#define N_MONO 150000
#define N_CLEAV 100000
#define N_FRAG 80000
#define N_FRAG_PAD 80128     // 313 * 256
#define N_OUT 40000
#define M_CLEAV_PAD 100352   // 448 * 224

static __device__ __forceinline__ u16 f2bf(float f) {
  u32 u = __float_as_uint(f);
  u32 r = (u + 0x7FFFu + ((u >> 16) & 1u)) >> 16;
  return (u16)r;
}
static __device__ __forceinline__ float bf2f(u16 b) {
  return __uint_as_float(((u32)b) << 16);
}
static __device__ __forceinline__ float sigmoidf(float x) {
  return __frcp_rn(1.0f + __expf(-x));
}
static __device__ __forceinline__ float fast_tanh(float x) {
  return 1.0f - 2.0f * __frcp_rn(__expf(2.0f * x) + 1.0f);
}
static __device__ __forceinline__ void async_copy16(const u16* g, const u16* l) {
  __builtin_amdgcn_global_load_lds(
      (const __attribute__((address_space(1))) u32*)g,
      (__attribute__((address_space(3))) u32*)l,
      16, 0, 0);
}

// ------- K0: weight cast + bias sum  +  feature bf16 + gate logits --------
__global__ __launch_bounds__(256) void feat_prep(
    const float* __restrict__ feat, const float* __restrict__ WgL,
    const float* __restrict__ WgR, u16* __restrict__ featb,
    float* __restrict__ glog,
    const float* __restrict__ Wih, const float* __restrict__ Whh,
    const float* __restrict__ bih, const float* __restrict__ bhh,
    u16* __restrict__ Wihb, u16* __restrict__ Whhb, float* __restrict__ bias) {
  int i = blockIdx.x * 256 + threadIdx.x;
  if (i < 1024 * 512) {
    Wihb[i] = f2bf(Wih[i]);
    if (i < 1024 * 256) Whhb[i] = f2bf(Whh[i]);
    if (i < 1024) bias[i] = bih[i] + bhh[i];
  }
  int wave = threadIdx.x >> 6, lane = threadIdx.x & 63;
  int n = blockIdx.x * 4 + wave;
  if (n >= N_MONO) return;
  float4 x = *(const float4*)(feat + (size_t)n * F + lane * 4);
  u32 lo = (u32)f2bf(x.x) | ((u32)f2bf(x.y) << 16);
  u32 hi = (u32)f2bf(x.z) | ((u32)f2bf(x.w) << 16);
  *(uint2*)(featb + (size_t)n * F + lane * 4) = make_uint2(lo, hi);
  float4 wl = *(const float4*)(WgL + lane * 4);
  float4 wr = *(const float4*)(WgR + lane * 4);
  float pl = x.x * wl.x + x.y * wl.y + x.z * wl.z + x.w * wl.w;
  float pr = x.x * wr.x + x.y * wr.y + x.z * wr.z + x.w * wr.w;
#pragma unroll
  for (int off = 32; off; off >>= 1) {
    pl += __shfl_xor(pl, off);
    pr += __shfl_xor(pr, off);
  }
  if (lane == 0) {
    glog[n * 2] = pl;
    glog[n * 2 + 1] = pr;
  }
}

// ---------------- K1: attention pulls -> cleav [N_CLEAV, 512] bf16 --------
__global__ __launch_bounds__(256) void attn_pull2(
    const u16* __restrict__ featb, const float* __restrict__ glog,
    const int* __restrict__ lostS, const int* __restrict__ retS,
    u16* __restrict__ cleav) {
  int wave = threadIdx.x >> 6, lane = threadIdx.x & 63;
  int n = blockIdx.x * 4 + wave;
  if (n >= N_CLEAV) return;
#pragma unroll
  for (int sg = 0; sg < 2; ++sg) {
    const int* src = sg ? retS : lostS;
    int4 ridx = *(const int4*)(src + n * 4);
    int r[4] = {ridx.x, ridx.y, ridx.z, ridx.w};
    ushort4 x4[4];
    float lg[4];
#pragma unroll
    for (int d = 0; d < 4; ++d) {
      x4[d] = *(const ushort4*)(featb + (size_t)r[d] * F + lane * 4);
      lg[d] = glog[r[d] * 2 + sg];
    }
    float mx = fmaxf(fmaxf(lg[0], lg[1]), fmaxf(lg[2], lg[3]));
    float e0 = __expf(lg[0] - mx), e1 = __expf(lg[1] - mx);
    float e2 = __expf(lg[2] - mx), e3 = __expf(lg[3] - mx);
    float inv = __frcp_rn(e0 + e1 + e2 + e3);
    float a[4] = {e0 * inv, e1 * inv, e2 * inv, e3 * inv};
    float acc[4] = {0.f, 0.f, 0.f, 0.f};
#pragma unroll
    for (int d = 0; d < 4; ++d) {
      const u16* xp = (const u16*)&x4[d];
#pragma unroll
      for (int k = 0; k < 4; k++) acc[k] += a[d] * bf2f(xp[k]);
    }
    u32 lo = (u32)f2bf(acc[0]) | ((u32)f2bf(acc[1]) << 16);
    u32 hi = (u32)f2bf(acc[2]) | ((u32)f2bf(acc[3]) << 16);
    *(uint2*)(cleav + (size_t)n * 512 + sg * 256 + lane * 4) = make_uint2(lo, hi);
  }
}

// ---------------- GEMM: 4-phase double-buffered MFMA ----------------------
// EPI==0 (GEMM-1, BM=224): C = acc + bias[n], plain layout (round-3 verified).
// EPI==1 (GEMM-2, BM=256): A = h1 coalesced, B = Whh gate-interleaved
//   (row = gate*256 + nstrip*64 + unit) so lane's j-quadrants hold the 4
//   gates of hidden unit hg = nstrip*64 + wn4*16 + l16.  After the K-loop,
//   the (now dead) 128-KiB LDS double buffer is reused to COOPERATIVELY
//   stage P[j1[m]] for the block's 256 rows x 64 units x 4 gates: 512
//   threads x 16 global_load_lds, each moving 8x128-B contiguous segments
//   (fixes round-4's 128x 2-B per-lane scattered gather).  k8-chunk XOR
//   swizzle (k8 ^ ((mloc>>2)&3), store-source + read involution) keeps the
//   LDS reads <=2-way conflicted.  Epilogue computes c2/h2, writes h2
//   panels [4][N_FRAG_PAD][64] bf16 + p2 partials (block-owned slots, no
//   atomics).  gates2 is never materialized.
template <int EPI, int K, int BM>
__global__ __launch_bounds__(512, 2) void gemm256(
    const u16* __restrict__ A, const u16* __restrict__ Bw,
    u16* __restrict__ C, const float* __restrict__ bias,
    const int* __restrict__ join, const u16* __restrict__ P,
    const u16* __restrict__ c1in, const float* __restrict__ Wg,
    u16* __restrict__ h2s, float* __restrict__ pp,
    int nper, int mstrips_valid) {
  constexpr int AREG = BM * 64;          // u16 units
  constexpr int BSZ = AREG + 16384;
  constexpr int WMH = BM / 2;            // per-M-wave rows
  constexpr int IB = BM / 32;            // per-wave 16-row blocks (7 or 8)
  constexpr int IB_HI = IB - 4;
  __shared__ u16 sh[2][BSZ];
  const int flat = blockIdx.x;
  const int xcd = flat & 7;
  const int w = flat >> 3;
  const int mstrip = xcd * nper + (w >> 2);
  const int nstrip = w & 3;
  if (mstrip >= mstrips_valid) return;
  const int m0 = mstrip * BM;
  const int n0 = nstrip * 256;

  const int tid = threadIdx.x;
  const int lane = tid & 63;
  const int wave = tid >> 6;
  const int quad = lane >> 4;
  const int l16 = lane & 15;
  const int s7 = l16 & 7;
  const int wm2 = wave >> 2;
  const int wn4 = wave & 3;

  const int arow = (wm2 * WMH + l16) * 64;
  const int brow = AREG + (wn4 * 64 + l16) * 64;
  const int coff0 = (quad ^ s7) * 8;
  const int coff1 = ((4 + quad) ^ s7) * 8;

  int sr[4], sw[4], dwv[4], bsrc[4];
#pragma unroll
  for (int r = 0; r < 4; r++) {
    int c = r * 512 + tid;
    int row = c >> 3;
    sr[r] = row;
    sw[r] = ((c & 7) ^ (row & 7)) * 8;
    dwv[r] = (r * 512 + (tid & ~63)) * 8;
    bsrc[r] = (EPI == 1)
        ? ((row >> 4) & 3) * 256 + nstrip * 64 + ((row >> 6) << 4) + (row & 15)
        : n0 + row;
  }
  const u16* Abase = A + (size_t)m0 * K;

  auto stageA = [&](int buf, int kt, int h) {
#pragma unroll
    for (int rr = 0; rr < 2; rr++) {
      int r = 2 * h + rr;
      if (r * 512 + tid < BM * 8)
        async_copy16(Abase + (size_t)sr[r] * K + kt * 64 + sw[r], &sh[buf][dwv[r]]);
    }
  };
  auto stageB = [&](int buf, int kt, int h) {
#pragma unroll
    for (int rr = 0; rr < 2; rr++) {
      int r = 2 * h + rr;
      async_copy16(Bw + (size_t)bsrc[r] * K + kt * 64 + sw[r], &sh[buf][AREG + dwv[r]]);
    }
  };

  f32x4 acc[IB][4];
#pragma unroll
  for (int i = 0; i < IB; i++)
#pragma unroll
    for (int j = 0; j < 4; j++) acc[i][j] = (f32x4){0.f, 0.f, 0.f, 0.f};

  constexpr int nK = K / 64;
  stageA(0, 0, 0); stageA(0, 0, 1); stageB(0, 0, 0); stageB(0, 0, 1);
  if (nK > 1) { stageB(1, 1, 0); stageB(1, 1, 1); }
  __builtin_amdgcn_s_waitcnt(0xF74);  // vmcnt(4)
  __builtin_amdgcn_s_barrier();

  bf16x8 a[4][2], b0[2][2], b1[2][2];
#pragma unroll
  for (int t = 0; t < nK; ++t) {
    const int bsel = t & 1;
    const u16* S = &sh[bsel][0];

    // ---- phase 1: i 0-3, j 0-1; stage A(t+1) half0.
#pragma unroll
    for (int i = 0; i < 4; i++) {
      a[i][0] = *(const bf16x8*)&S[arow + i * 1024 + coff0];
      a[i][1] = *(const bf16x8*)&S[arow + i * 1024 + coff1];
    }
#pragma unroll
    for (int j = 0; j < 2; j++) {
      b0[j][0] = *(const bf16x8*)&S[brow + j * 1024 + coff0];
      b0[j][1] = *(const bf16x8*)&S[brow + j * 1024 + coff1];
    }
    if (t + 1 < nK) stageA(bsel ^ 1, t + 1, 0);
    __builtin_amdgcn_s_waitcnt(0xC87F);  // lgkmcnt(8)
    __builtin_amdgcn_s_barrier();
    __builtin_amdgcn_s_waitcnt(0xC07F);  // lgkmcnt(0)
    __builtin_amdgcn_sched_barrier(0);
    __builtin_amdgcn_s_setprio(1);
#pragma unroll
    for (int i = 0; i < 4; i++)
#pragma unroll
      for (int j = 0; j < 2; j++) {
        acc[i][j] = __builtin_amdgcn_mfma_f32_16x16x32_bf16(a[i][0], b0[j][0], acc[i][j], 0, 0, 0);
        acc[i][j] = __builtin_amdgcn_mfma_f32_16x16x32_bf16(a[i][1], b0[j][1], acc[i][j], 0, 0, 0);
      }
    __builtin_amdgcn_s_setprio(0);
    __builtin_amdgcn_s_barrier();

    // ---- phase 2: i 0-3, j 2-3; stage A(t+1) half1.
#pragma unroll
    for (int j = 0; j < 2; j++) {
      b1[j][0] = *(const bf16x8*)&S[brow + (2 + j) * 1024 + coff0];
      b1[j][1] = *(const bf16x8*)&S[brow + (2 + j) * 1024 + coff1];
    }
    if (t + 1 < nK) stageA(bsel ^ 1, t + 1, 1);
    __builtin_amdgcn_s_barrier();
    __builtin_amdgcn_s_waitcnt(0xC07F);
    __builtin_amdgcn_sched_barrier(0);
    __builtin_amdgcn_s_setprio(1);
#pragma unroll
    for (int i = 0; i < 4; i++)
#pragma unroll
      for (int j = 0; j < 2; j++) {
        acc[i][2 + j] = __builtin_amdgcn_mfma_f32_16x16x32_bf16(a[i][0], b1[j][0], acc[i][2 + j], 0, 0, 0);
        acc[i][2 + j] = __builtin_amdgcn_mfma_f32_16x16x32_bf16(a[i][1], b1[j][1], acc[i][2 + j], 0, 0, 0);
      }
    __builtin_amdgcn_s_setprio(0);
    __builtin_amdgcn_s_barrier();

    // ---- phase 3: i 4.., j 0-1; stage B(t+2) half0.
#pragma unroll
    for (int i = 0; i < IB_HI; i++) {
      a[i][0] = *(const bf16x8*)&S[arow + (4 + i) * 1024 + coff0];
      a[i][1] = *(const bf16x8*)&S[arow + (4 + i) * 1024 + coff1];
    }
    if (t + 2 < nK) stageB(bsel, t + 2, 0);
    __builtin_amdgcn_s_barrier();
    __builtin_amdgcn_s_waitcnt(0xC07F);
    __builtin_amdgcn_sched_barrier(0);
    __builtin_amdgcn_s_setprio(1);
#pragma unroll
    for (int i = 0; i < IB_HI; i++)
#pragma unroll
      for (int j = 0; j < 2; j++) {
        acc[4 + i][j] = __builtin_amdgcn_mfma_f32_16x16x32_bf16(a[i][0], b0[j][0], acc[4 + i][j], 0, 0, 0);
        acc[4 + i][j] = __builtin_amdgcn_mfma_f32_16x16x32_bf16(a[i][1], b0[j][1], acc[4 + i][j], 0, 0, 0);
      }
    __builtin_amdgcn_s_setprio(0);
    __builtin_amdgcn_s_barrier();

    // ---- phase 4: i 4.., j 2-3; stage B(t+2) half1; boundary vmcnt.
    if (t + 2 < nK) stageB(bsel, t + 2, 1);
    __builtin_amdgcn_s_barrier();
    __builtin_amdgcn_s_setprio(1);
#pragma unroll
    for (int i = 0; i < IB_HI; i++)
#pragma unroll
      for (int j = 0; j < 2; j++) {
        acc[4 + i][2 + j] = __builtin_amdgcn_mfma_f32_16x16x32_bf16(a[i][0], b1[j][0], acc[4 + i][2 + j], 0, 0, 0);
        acc[4 + i][2 + j] = __builtin_amdgcn_mfma_f32_16x16x32_bf16(a[i][1], b1[j][1], acc[4 + i][2 + j], 0, 0, 0);
      }
    __builtin_amdgcn_s_setprio(0);
    if (t + 2 < nK) __builtin_amdgcn_s_waitcnt(0xF74);  // vmcnt(4)
    else            __builtin_amdgcn_s_waitcnt(0xF70);  // vmcnt(0)
    __builtin_amdgcn_s_barrier();
  }

  if constexpr (EPI == 0) {
    float badd[4];
#pragma unroll
    for (int j = 0; j < 4; j++)
      badd[j] = bias[n0 + wn4 * 64 + j * 16 + l16];
#pragma unroll
    for (int i = 0; i < IB; i++) {
      const int mrow = m0 + wm2 * WMH + i * 16 + quad * 4;
#pragma unroll
      for (int j = 0; j < 4; j++) {
        const int n = n0 + wn4 * 64 + j * 16 + l16;
#pragma unroll
        for (int r = 0; r < 4; r++)
          C[(size_t)(mrow + r) * 1024 + n] = f2bf(acc[i][j][r] + badd[j]);
      }
    }
  } else {
    // ---- cooperative LDS-staged P[j1] gather (after final barrier the
    // double buffers are dead; Pstage = [BM m][4 g][64 hu-swz] = 128 KiB).
    u16* Pl = &sh[0][0];
    const int hgl = wn4 * 16 + l16;
    const int hg = nstrip * 64 + hgl;
    // c1 prefetch (m-indexed, independent addresses)
    u16 c1r[IB][4];
#pragma unroll
    for (int i = 0; i < IB; i++)
#pragma unroll
      for (int r = 0; r < 4; r++) {
        const int m = m0 + wm2 * WMH + i * 16 + quad * 4 + r;
        c1r[i][r] = c1in[(size_t)m * 256 + hg];
      }
    // indices: iteration it covers rows mrow = it*16 + (tid>>5)
    int jrow[BM / 16];
#pragma unroll
    for (int it = 0; it < BM / 16; ++it) {
      const int mm = m0 + it * 16 + (tid >> 5);
      jrow[it] = join[2 * (mm < N_FRAG ? mm : N_FRAG - 1) + 1];
    }
#pragma unroll
    for (int it = 0; it < BM / 16; ++it) {
      const int c = it * 512 + tid;
      const int mloc = c >> 5;
      const int g = (c >> 3) & 3;
      const int k8 = (c & 7) ^ ((mloc >> 2) & 3);   // store-side swizzle
      async_copy16(P + (size_t)jrow[it] * 1024 + g * 256 + nstrip * 64 + k8 * 8,
                   &Pl[(size_t)(it * 512 + (tid & ~63)) * 8]);
    }
    __builtin_amdgcn_s_waitcnt(0xF70);  // vmcnt(0): P-stage + c1 landed
    __builtin_amdgcn_s_barrier();
    __builtin_amdgcn_sched_barrier(0);

    const float wgv = Wg[hg];
#pragma unroll
    for (int i = 0; i < IB; i++) {
#pragma unroll
      for (int r = 0; r < 4; r++) {
        const int mloc = wm2 * WMH + i * 16 + quad * 4 + r;
        const int m = m0 + mloc;
        const u16* pr = &Pl[mloc * 256 + (hgl ^ (((mloc >> 2) & 3) << 3))];
        float gi = acc[i][0][r] + bf2f(pr[0]);
        float gf = acc[i][1][r] + bf2f(pr[64]);
        float gg = acc[i][2][r] + bf2f(pr[128]);
        float go = acc[i][3][r] + bf2f(pr[192]);
        float c1v = bf2f(c1r[i][r]);
        float cv = sigmoidf(gf) * c1v + sigmoidf(gi) * fast_tanh(gg);
        float hv = sigmoidf(go) * fast_tanh(cv);
        h2s[((size_t)nstrip * N_FRAG_PAD + m) * 64 + hgl] = f2bf(hv);
        float p = bf2f(f2bf(hv)) * wgv;
        p += __shfl_xor(p, 1); p += __shfl_xor(p, 2);
        p += __shfl_xor(p, 4); p += __shfl_xor(p, 8);
        if (l16 == 0) pp[(size_t)m * 16 + nstrip * 4 + wn4] = p;
      }
    }
  }
}

// ---------------- K3: LSTM step 1 + p1 logit, wave-per-fragment -----------
__global__ __launch_bounds__(256) void lstm_step1(
    const u16* __restrict__ P, const int* __restrict__ join,
    const float* __restrict__ Wg, u16* __restrict__ h1,
    u16* __restrict__ c1, float* __restrict__ p1) {
  int wave = threadIdx.x >> 6, lane = threadIdx.x & 63;
  int m = blockIdx.x * 4 + wave;
  if (m >= N_FRAG) return;
  int j0 = join[2 * m];
  const u16* row = P + (size_t)j0 * 1024 + lane * 4;
  ushort4 iv = *(const ushort4*)(row);
  ushort4 gv = *(const ushort4*)(row + 512);
  ushort4 ov = *(const ushort4*)(row + 768);
  float4 wg = *(const float4*)(Wg + lane * 4);
  const u16* ivp = (const u16*)&iv;
  const u16* gvp = (const u16*)&gv;
  const u16* ovp = (const u16*)&ov;
  const float* wgp = (const float*)&wg;
  ushort4 h4, c4;
  u16* h4p = (u16*)&h4;
  u16* c4p = (u16*)&c4;
  float pl = 0.f;
#pragma unroll
  for (int k = 0; k < 4; k++) {
    float c = sigmoidf(bf2f(ivp[k])) * fast_tanh(bf2f(gvp[k]));
    float hv = sigmoidf(bf2f(ovp[k])) * fast_tanh(c);
    h4p[k] = f2bf(hv);
    c4p[k] = f2bf(c);
    pl += bf2f(h4p[k]) * wgp[k];
  }
#pragma unroll
  for (int off = 32; off; off >>= 1) pl += __shfl_xor(pl, off);
  *(ushort4*)(h1 + (size_t)m * 256 + lane * 4) = h4;
  *(ushort4*)(c1 + (size_t)m * 256 + lane * 4) = c4;
  if (lane == 0) p1[m] = pl;
}

// ------- K5: attention over {h1,h2} + output head (light) -----------------
__global__ __launch_bounds__(256) void lstm_attn_out(
    const u16* __restrict__ h1, const u16* __restrict__ h2s,
    const float* __restrict__ p1, const float* __restrict__ p2p,
    const float* __restrict__ Wout, const float* __restrict__ bout,
    float* __restrict__ frag_out) {
  int wave = threadIdx.x >> 6, lane = threadIdx.x & 63;
  int m = blockIdx.x * 4 + wave;
  if (m >= N_FRAG) return;
  float4 q = *(const float4*)(p2p + (size_t)m * 16 + (lane & 3) * 4);
  float p2 = q.x + q.y + q.z + q.w;
  p2 += __shfl_xor(p2, 1);
  p2 += __shfl_xor(p2, 2);
  float p1v = p1[m];
  float mx = fmaxf(p1v, p2);
  float e1 = __expf(p1v - mx), e2 = __expf(p2 - mx);
  float inv = __frcp_rn(e1 + e2);
  float a1 = e1 * inv, a2 = e2 * inv;

  ushort4 h1v = *(const ushort4*)(h1 + (size_t)m * 256 + lane * 4);
  ushort4 h2v = *(const ushort4*)(h2s + ((size_t)(lane >> 4) * N_FRAG_PAD + m) * 64 + (lane & 15) * 4);
  const u16* h1p = (const u16*)&h1v;
  const u16* h2p = (const u16*)&h2v;

  float acc[8];
#pragma unroll
  for (int t = 0; t < 8; t++) acc[t] = 0.f;
#pragma unroll
  for (int k = 0; k < 4; k++) {
    float frag = a1 * bf2f(h1p[k]) + a2 * bf2f(h2p[k]);
    int h = lane * 4 + k;
    float4 w0 = *(const float4*)(Wout + h * 8);
    float4 w1 = *(const float4*)(Wout + h * 8 + 4);
    acc[0] += frag * w0.x; acc[1] += frag * w0.y;
    acc[2] += frag * w0.z; acc[3] += frag * w0.w;
    acc[4] += frag * w1.x; acc[5] += frag * w1.y;
    acc[6] += frag * w1.z; acc[7] += frag * w1.w;
  }
#pragma unroll
  for (int off = 32; off; off >>= 1)
#pragma unroll
    for (int t = 0; t < 8; t++) acc[t] += __shfl_xor(acc[t], off);
  if (lane == 0) {
    float4 o0, o1;
    o0.x = fmaxf(acc[0] + bout[0], 0.f);
    o0.y = fmaxf(acc[1] + bout[1], 0.f);
    o0.z = fmaxf(acc[2] + bout[2], 0.f);
    o0.w = fmaxf(acc[3] + bout[3], 0.f);
    o1.x = fmaxf(acc[4] + bout[4], 0.f);
    o1.y = fmaxf(acc[5] + bout[5], 0.f);
    o1.z = fmaxf(acc[6] + bout[6], 0.f);
    o1.w = fmaxf(acc[7] + bout[7], 0.f);
    *(float4*)(frag_out + (size_t)m * 8) = o0;
    *(float4*)(frag_out + (size_t)m * 8 + 4) = o1;
  }
}

// ---------------- K6: combine scatter-sum ---------------------------------
__global__ __launch_bounds__(256) void scatter_sum(
    const float* __restrict__ frag_out, const int* __restrict__ comb,
    float* __restrict__ out) {
  int tid = blockIdx.x * 256 + threadIdx.x;
  if (tid >= N_OUT * 8) return;
  int n = tid >> 3, t = tid & 7;
  float s = 0.f;
#pragma unroll
  for (int d = 0; d < 4; d++) {
    int f = comb[n * 4 + d];
    s += frag_out[(size_t)f * 8 + t];
  }
  out[tid] = s;
}

extern "C" void kernel_launch(void* const* d_in, const int* in_sizes, int n_in,
                              void* d_out, int out_size, void* d_ws, size_t ws_size,
                              hipStream_t stream) {
  const float* feature = (const float*)d_in[0];
  const float* WgL = (const float*)d_in[1];
  const float* WgR = (const float*)d_in[2];
  const float* Wih = (const float*)d_in[3];
  const float* Whh = (const float*)d_in[4];
  const float* bih = (const float*)d_in[5];
  const float* bhh = (const float*)d_in[6];
  const float* Wgf = (const float*)d_in[7];
  const float* Wout = (const float*)d_in[8];
  const float* bout = (const float*)d_in[9];
  const int* lostS = (const int*)d_in[10];
  const int* retS = (const int*)d_in[11];
  const int* joinS = (const int*)d_in[12];
  const int* combS = (const int*)d_in[13];
  float* out = (float*)d_out;

  char* ws = (char*)d_ws;
  size_t off = 0;
  auto alloc = [&](size_t bytes) -> char* {
    char* p = ws + off;
    off = (off + bytes + 255) & ~(size_t)255;
    return p;
  };
  u16* Wihb = (u16*)alloc((size_t)1024 * 512 * 2);
  u16* Whhb = (u16*)alloc((size_t)1024 * 256 * 2);
  float* bias = (float*)alloc(1024 * 4);
  u16* P = (u16*)alloc((size_t)M_CLEAV_PAD * 1024 * 2);
  u16* h1 = (u16*)alloc((size_t)N_FRAG_PAD * 256 * 2);
  u16* c1 = (u16*)alloc((size_t)N_FRAG_PAD * 256 * 2);
  u16* h2s = (u16*)alloc((size_t)4 * N_FRAG_PAD * 64 * 2);
  float* p2p = (float*)alloc((size_t)N_FRAG_PAD * 16 * 4);
  float* p1 = (float*)alloc((size_t)N_FRAG_PAD * 4);
  float* frag_out = (float*)alloc((size_t)N_FRAG * 8 * 4);
  u16* cleav = (u16*)alloc((size_t)M_CLEAV_PAD * 512 * 2);
  // featb (76.8 MB) + glog (1.2 MB) alias the P region: dead once
  // attn_pull2 completes, before GEMM-1 writes P (stream-ordered).
  u16* featb = P;
  float* glog = (float*)(P + (size_t)N_MONO * F);

  feat_prep<<<(N_MONO + 3) / 4, 256, 0, stream>>>(
      feature, WgL, WgR, featb, glog, Wih, Whh, bih, bhh, Wihb, Whhb, bias);
  attn_pull2<<<N_CLEAV / 4, 256, 0, stream>>>(featb, glog, lostS, retS, cleav);
  // GEMM-1: M=100352 = 448*224 strips, 56/XCD, 1792 blocks = 7/CU exact
  gemm256<0, 512, 224><<<1792, 512, 0, stream>>>(
      cleav, Wihb, P, bias, nullptr, nullptr, nullptr, nullptr, nullptr, nullptr,
      56, 448);
  lstm_step1<<<N_FRAG / 4, 256, 0, stream>>>(P, joinS, Wgf, h1, c1, p1);
  // GEMM-2 (fused LSTM step-2, LDS-staged P gather): M=80128 -> 313 strips,
  // 320 virtual (40/XCD), tail early-exits; 1280 blocks = 5/CU.
  gemm256<1, 256, 256><<<1280, 512, 0, stream>>>(
      h1, Whhb, nullptr, nullptr, joinS, P, c1, Wgf, h2s, p2p,
      40, 313);
  lstm_attn_out<<<N_FRAG / 4, 256, 0, stream>>>(
      h1, h2s, p1, p2p, Wout, bout, frag_out);
  scatter_sum<<<(N_OUT * 8 + 255) / 256, 256, 0, stream>>>(frag_out, combS, out);
}

// Round 7
// 690.878 us; speedup vs baseline: 1.1176x; 1.0148x over previous
//
#include <hip/hip_runtime.h>

typedef unsigned short u16;
typedef unsigned int u32;
typedef float f32x4 __attribute__((ext_vector_type(4)));
typedef __bf16 bf16x8 __attribute__((ext_vector_type(8)));

#define F 256
#define T_OUT 8
#define N_MONO 150000
#define N_CLEAV 100000
#define N_FRAG 80000
#define N_FRAG_PAD 80128     // 626 * 128
#define N_OUT 40000
#define M_CLEAV_PAD 100352   // 448 * 224

static __device__ __forceinline__ u16 f2bf(float f) {
  u32 u = __float_as_uint(f);
  u32 r = (u + 0x7FFFu + ((u >> 16) & 1u)) >> 16;
  return (u16)r;
}
static __device__ __forceinline__ float bf2f(u16 b) {
  return __uint_as_float(((u32)b) << 16);
}
static __device__ __forceinline__ float sigmoidf(float x) {
  return __frcp_rn(1.0f + __expf(-x));
}
static __device__ __forceinline__ float fast_tanh(float x) {
  return 1.0f - 2.0f * __frcp_rn(__expf(2.0f * x) + 1.0f);
}
static __device__ __forceinline__ void async_copy16(const u16* g, const u16* l) {
  __builtin_amdgcn_global_load_lds(
      (const __attribute__((address_space(1))) u32*)g,
      (__attribute__((address_space(3))) u32*)l,
      16, 0, 0);
}

// ------- K0: weight cast + bias sum  +  feature bf16 + gate logits --------
__global__ __launch_bounds__(256) void feat_prep(
    const float* __restrict__ feat, const float* __restrict__ WgL,
    const float* __restrict__ WgR, u16* __restrict__ featb,
    float* __restrict__ glog,
    const float* __restrict__ Wih, const float* __restrict__ Whh,
    const float* __restrict__ bih, const float* __restrict__ bhh,
    u16* __restrict__ Wihb, u16* __restrict__ Whhb, float* __restrict__ bias) {
  int i = blockIdx.x * 256 + threadIdx.x;
  if (i < 1024 * 512) {
    Wihb[i] = f2bf(Wih[i]);
    if (i < 1024 * 256) Whhb[i] = f2bf(Whh[i]);
    if (i < 1024) bias[i] = bih[i] + bhh[i];
  }
  int wave = threadIdx.x >> 6, lane = threadIdx.x & 63;
  int n = blockIdx.x * 4 + wave;
  if (n >= N_MONO) return;
  float4 x = *(const float4*)(feat + (size_t)n * F + lane * 4);
  u32 lo = (u32)f2bf(x.x) | ((u32)f2bf(x.y) << 16);
  u32 hi = (u32)f2bf(x.z) | ((u32)f2bf(x.w) << 16);
  *(uint2*)(featb + (size_t)n * F + lane * 4) = make_uint2(lo, hi);
  float4 wl = *(const float4*)(WgL + lane * 4);
  float4 wr = *(const float4*)(WgR + lane * 4);
  float pl = x.x * wl.x + x.y * wl.y + x.z * wl.z + x.w * wl.w;
  float pr = x.x * wr.x + x.y * wr.y + x.z * wr.z + x.w * wr.w;
#pragma unroll
  for (int off = 32; off; off >>= 1) {
    pl += __shfl_xor(pl, off);
    pr += __shfl_xor(pr, off);
  }
  if (lane == 0) {
    glog[n * 2] = pl;
    glog[n * 2 + 1] = pr;
  }
}

// ---------------- K1: attention pulls -> cleav [N_CLEAV, 512] bf16 --------
__global__ __launch_bounds__(256) void attn_pull2(
    const u16* __restrict__ featb, const float* __restrict__ glog,
    const int* __restrict__ lostS, const int* __restrict__ retS,
    u16* __restrict__ cleav) {
  int wave = threadIdx.x >> 6, lane = threadIdx.x & 63;
  int n = blockIdx.x * 4 + wave;
  if (n >= N_CLEAV) return;
#pragma unroll
  for (int sg = 0; sg < 2; ++sg) {
    const int* src = sg ? retS : lostS;
    int4 ridx = *(const int4*)(src + n * 4);
    int r[4] = {ridx.x, ridx.y, ridx.z, ridx.w};
    ushort4 x4[4];
    float lg[4];
#pragma unroll
    for (int d = 0; d < 4; ++d) {
      x4[d] = *(const ushort4*)(featb + (size_t)r[d] * F + lane * 4);
      lg[d] = glog[r[d] * 2 + sg];
    }
    float mx = fmaxf(fmaxf(lg[0], lg[1]), fmaxf(lg[2], lg[3]));
    float e0 = __expf(lg[0] - mx), e1 = __expf(lg[1] - mx);
    float e2 = __expf(lg[2] - mx), e3 = __expf(lg[3] - mx);
    float inv = __frcp_rn(e0 + e1 + e2 + e3);
    float a[4] = {e0 * inv, e1 * inv, e2 * inv, e3 * inv};
    float acc[4] = {0.f, 0.f, 0.f, 0.f};
#pragma unroll
    for (int d = 0; d < 4; ++d) {
      const u16* xp = (const u16*)&x4[d];
#pragma unroll
      for (int k = 0; k < 4; k++) acc[k] += a[d] * bf2f(xp[k]);
    }
    u32 lo = (u32)f2bf(acc[0]) | ((u32)f2bf(acc[1]) << 16);
    u32 hi = (u32)f2bf(acc[2]) | ((u32)f2bf(acc[3]) << 16);
    *(uint2*)(cleav + (size_t)n * 512 + sg * 256 + lane * 4) = make_uint2(lo, hi);
  }
}

// ---------------- GEMM-1: P = cleav @ Wih^T + bias (round-3 verified) -----
// BM=224 x 256 tile, BK=64, 8 waves, 4-phase double-buffered, vmcnt(4).
__global__ __launch_bounds__(512, 2) void gemm224(
    const u16* __restrict__ A, const u16* __restrict__ Bw,
    u16* __restrict__ C, const float* __restrict__ bias,
    int nper, int mstrips_valid) {
  constexpr int K = 512, BM = 224;
  constexpr int AREG = BM * 64;
  constexpr int BSZ = AREG + 16384;
  constexpr int WMH = BM / 2;
  constexpr int IB = BM / 32;            // 7
  constexpr int IB_HI = IB - 4;          // 3
  __shared__ u16 sh[2][BSZ];
  const int flat = blockIdx.x;
  const int xcd = flat & 7;
  const int w = flat >> 3;
  const int mstrip = xcd * nper + (w >> 2);
  const int nstrip = w & 3;
  if (mstrip >= mstrips_valid) return;
  const int m0 = mstrip * BM;
  const int n0 = nstrip * 256;

  const int tid = threadIdx.x;
  const int lane = tid & 63;
  const int wave = tid >> 6;
  const int quad = lane >> 4;
  const int l16 = lane & 15;
  const int s7 = l16 & 7;
  const int wm2 = wave >> 2;
  const int wn4 = wave & 3;

  const int arow = (wm2 * WMH + l16) * 64;
  const int brow = AREG + (wn4 * 64 + l16) * 64;
  const int coff0 = (quad ^ s7) * 8;
  const int coff1 = ((4 + quad) ^ s7) * 8;

  int sr[4], sw[4], dwv[4];
#pragma unroll
  for (int r = 0; r < 4; r++) {
    int c = r * 512 + tid;
    sr[r] = c >> 3;
    sw[r] = ((c & 7) ^ ((c >> 3) & 7)) * 8;
    dwv[r] = (r * 512 + (tid & ~63)) * 8;
  }
  const u16* Abase = A + (size_t)m0 * K;
  const u16* Bbase = Bw + (size_t)n0 * K;

  auto stageA = [&](int buf, int kt, int h) {
#pragma unroll
    for (int rr = 0; rr < 2; rr++) {
      int r = 2 * h + rr;
      if (r * 512 + tid < BM * 8)
        async_copy16(Abase + (size_t)sr[r] * K + kt * 64 + sw[r], &sh[buf][dwv[r]]);
    }
  };
  auto stageB = [&](int buf, int kt, int h) {
#pragma unroll
    for (int rr = 0; rr < 2; rr++) {
      int r = 2 * h + rr;
      async_copy16(Bbase + (size_t)sr[r] * K + kt * 64 + sw[r], &sh[buf][AREG + dwv[r]]);
    }
  };

  f32x4 acc[IB][4];
#pragma unroll
  for (int i = 0; i < IB; i++)
#pragma unroll
    for (int j = 0; j < 4; j++) acc[i][j] = (f32x4){0.f, 0.f, 0.f, 0.f};

  constexpr int nK = K / 64;
  stageA(0, 0, 0); stageA(0, 0, 1); stageB(0, 0, 0); stageB(0, 0, 1);
  stageB(1, 1, 0); stageB(1, 1, 1);
  __builtin_amdgcn_s_waitcnt(0xF74);
  __builtin_amdgcn_s_barrier();

  bf16x8 a[4][2], b0[2][2], b1[2][2];
#pragma unroll
  for (int t = 0; t < nK; ++t) {
    const int bsel = t & 1;
    const u16* S = &sh[bsel][0];

#pragma unroll
    for (int i = 0; i < 4; i++) {
      a[i][0] = *(const bf16x8*)&S[arow + i * 1024 + coff0];
      a[i][1] = *(const bf16x8*)&S[arow + i * 1024 + coff1];
    }
#pragma unroll
    for (int j = 0; j < 2; j++) {
      b0[j][0] = *(const bf16x8*)&S[brow + j * 1024 + coff0];
      b0[j][1] = *(const bf16x8*)&S[brow + j * 1024 + coff1];
    }
    if (t + 1 < nK) stageA(bsel ^ 1, t + 1, 0);
    __builtin_amdgcn_s_waitcnt(0xC87F);
    __builtin_amdgcn_s_barrier();
    __builtin_amdgcn_s_waitcnt(0xC07F);
    __builtin_amdgcn_sched_barrier(0);
    __builtin_amdgcn_s_setprio(1);
#pragma unroll
    for (int i = 0; i < 4; i++)
#pragma unroll
      for (int j = 0; j < 2; j++) {
        acc[i][j] = __builtin_amdgcn_mfma_f32_16x16x32_bf16(a[i][0], b0[j][0], acc[i][j], 0, 0, 0);
        acc[i][j] = __builtin_amdgcn_mfma_f32_16x16x32_bf16(a[i][1], b0[j][1], acc[i][j], 0, 0, 0);
      }
    __builtin_amdgcn_s_setprio(0);
    __builtin_amdgcn_s_barrier();

#pragma unroll
    for (int j = 0; j < 2; j++) {
      b1[j][0] = *(const bf16x8*)&S[brow + (2 + j) * 1024 + coff0];
      b1[j][1] = *(const bf16x8*)&S[brow + (2 + j) * 1024 + coff1];
    }
    if (t + 1 < nK) stageA(bsel ^ 1, t + 1, 1);
    __builtin_amdgcn_s_barrier();
    __builtin_amdgcn_s_waitcnt(0xC07F);
    __builtin_amdgcn_sched_barrier(0);
    __builtin_amdgcn_s_setprio(1);
#pragma unroll
    for (int i = 0; i < 4; i++)
#pragma unroll
      for (int j = 0; j < 2; j++) {
        acc[i][2 + j] = __builtin_amdgcn_mfma_f32_16x16x32_bf16(a[i][0], b1[j][0], acc[i][2 + j], 0, 0, 0);
        acc[i][2 + j] = __builtin_amdgcn_mfma_f32_16x16x32_bf16(a[i][1], b1[j][1], acc[i][2 + j], 0, 0, 0);
      }
    __builtin_amdgcn_s_setprio(0);
    __builtin_amdgcn_s_barrier();

#pragma unroll
    for (int i = 0; i < IB_HI; i++) {
      a[i][0] = *(const bf16x8*)&S[arow + (4 + i) * 1024 + coff0];
      a[i][1] = *(const bf16x8*)&S[arow + (4 + i) * 1024 + coff1];
    }
    if (t + 2 < nK) stageB(bsel, t + 2, 0);
    __builtin_amdgcn_s_barrier();
    __builtin_amdgcn_s_waitcnt(0xC07F);
    __builtin_amdgcn_sched_barrier(0);
    __builtin_amdgcn_s_setprio(1);
#pragma unroll
    for (int i = 0; i < IB_HI; i++)
#pragma unroll
      for (int j = 0; j < 2; j++) {
        acc[4 + i][j] = __builtin_amdgcn_mfma_f32_16x16x32_bf16(a[i][0], b0[j][0], acc[4 + i][j], 0, 0, 0);
        acc[4 + i][j] = __builtin_amdgcn_mfma_f32_16x16x32_bf16(a[i][1], b0[j][1], acc[4 + i][j], 0, 0, 0);
      }
    __builtin_amdgcn_s_setprio(0);
    __builtin_amdgcn_s_barrier();

    if (t + 2 < nK) stageB(bsel, t + 2, 1);
    __builtin_amdgcn_s_barrier();
    __builtin_amdgcn_s_setprio(1);
#pragma unroll
    for (int i = 0; i < IB_HI; i++)
#pragma unroll
      for (int j = 0; j < 2; j++) {
        acc[4 + i][2 + j] = __builtin_amdgcn_mfma_f32_16x16x32_bf16(a[i][0], b1[j][0], acc[4 + i][2 + j], 0, 0, 0);
        acc[4 + i][2 + j] = __builtin_amdgcn_mfma_f32_16x16x32_bf16(a[i][1], b1[j][1], acc[4 + i][2 + j], 0, 0, 0);
      }
    __builtin_amdgcn_s_setprio(0);
    if (t + 2 < nK) __builtin_amdgcn_s_waitcnt(0xF74);
    else            __builtin_amdgcn_s_waitcnt(0xF70);
    __builtin_amdgcn_s_barrier();
  }

  float badd[4];
#pragma unroll
  for (int j = 0; j < 4; j++)
    badd[j] = bias[n0 + wn4 * 64 + j * 16 + l16];
#pragma unroll
  for (int i = 0; i < IB; i++) {
    const int mrow = m0 + wm2 * WMH + i * 16 + quad * 4;
#pragma unroll
    for (int j = 0; j < 4; j++) {
      const int n = n0 + wn4 * 64 + j * 16 + l16;
#pragma unroll
      for (int r = 0; r < 4; r++)
        C[(size_t)(mrow + r) * 1024 + n] = f2bf(acc[i][j][r] + badd[j]);
    }
  }
}

// ---------------- K3: LSTM step 1, wave-per-fragment ----------------------
// Zero-fills pad rows [N_FRAG, N_FRAG_PAD) so g2fuse reads defined data.
__global__ __launch_bounds__(256) void lstm_step1(
    const u16* __restrict__ P, const int* __restrict__ join,
    u16* __restrict__ h1, u16* __restrict__ c1) {
  int wave = threadIdx.x >> 6, lane = threadIdx.x & 63;
  int m = blockIdx.x * 4 + wave;
  if (m >= N_FRAG_PAD) return;
  if (m >= N_FRAG) {
    *(ushort4*)(h1 + (size_t)m * 256 + lane * 4) = make_ushort4(0, 0, 0, 0);
    *(ushort4*)(c1 + (size_t)m * 256 + lane * 4) = make_ushort4(0, 0, 0, 0);
    return;
  }
  int j0 = join[2 * m];
  const u16* row = P + (size_t)j0 * 1024 + lane * 4;
  ushort4 iv = *(const ushort4*)(row);
  ushort4 gv = *(const ushort4*)(row + 512);
  ushort4 ov = *(const ushort4*)(row + 768);
  const u16* ivp = (const u16*)&iv;
  const u16* gvp = (const u16*)&gv;
  const u16* ovp = (const u16*)&ov;
  ushort4 h4, c4;
  u16* h4p = (u16*)&h4;
  u16* c4p = (u16*)&c4;
#pragma unroll
  for (int k = 0; k < 4; k++) {
    float c = sigmoidf(bf2f(ivp[k])) * fast_tanh(bf2f(gvp[k]));
    float hv = sigmoidf(bf2f(ovp[k])) * fast_tanh(c);
    h4p[k] = f2bf(hv);
    c4p[k] = f2bf(c);
  }
  *(ushort4*)(h1 + (size_t)m * 256 + lane * 4) = h4;
  *(ushort4*)(c1 + (size_t)m * 256 + lane * 4) = c4;
}

// ------- G2 fused: gates2 = h1 @ Whh^T (+P[j1], +c1) -> h2  ---------------
// 128x128 tile, BK=32, 256 thr, triple-buffered LDS (48 KiB, 3 blocks/CU so
// neighbor blocks' main loops overlap this block's epilogue latency).
// B gate-interleaved: staged row `row` -> Whh row ((row>>4)&3)*256 +
// nstrip*32 + ((row>>6)<<4) + (row&15); read fragment (wnq,j,l16) then holds
// gate j of unit u = nstrip*32 + wnq*16 + l16.
// Epilogue: stage P[j1[m]] 128rows x 4g x 32u = 32 KiB into dead LDS via 8
// coalesced global_load_lds/thread (chunk XOR swizzle, source+read
// involution), c1 via 32-B-segment reg loads, then pure-VALU LSTM step-2;
// writes h2s[m][256] bf16 only (logits computed later in lstm_attn_out).
// j1 indices preloaded BEFORE the K-loop: first-iteration vmcnt(4) then
// waits jrow(8)+stage0(4)=12 of 16 outstanding -> stage(0) landed, exactly
// as in the verified R0 schedule.
__global__ __launch_bounds__(256, 3) void g2fuse(
    const u16* __restrict__ h1A, const u16* __restrict__ Whhb,
    const u16* __restrict__ P, const int* __restrict__ join,
    const u16* __restrict__ c1in, u16* __restrict__ h2s) {
  constexpr int K = 256;
  __shared__ u16 sh[6][128 * 32];   // A bufs 0-2, B bufs 3-5 (48 KiB)
  const int w = blockIdx.x;
  const int mstrip = w >> 3;        // 0..625
  const int nstrip = w & 7;
  const int m0 = mstrip * 128;

  const int tid = threadIdx.x;
  const int lane = tid & 63;
  const int wave = tid >> 6;
  const int quad = lane >> 4;
  const int l16 = lane & 15;
  const int wm = (wave & 1) * 64;
  const int wnq = wave >> 1;        // 0..1
  const int wn = wnq * 64;

  int srow[2], skoff[2], ldsoff[2], brow[2];
#pragma unroll
  for (int jj = 0; jj < 2; jj++) {
    int c = jj * 256 + tid;
    int row = c >> 2;
    srow[jj] = row;
    skoff[jj] = ((c & 3) ^ ((c >> 3) & 3)) * 8;
    ldsoff[jj] = (jj * 256 + (tid & ~63)) * 8;
    brow[jj] = ((row >> 4) & 3) * 256 + nstrip * 32 + ((row >> 6) << 4) + (row & 15);
  }
  const u16* Abase = h1A + (size_t)m0 * K;

  // j1 indices for the epilogue stage: round rd covers mloc = rd*16+(tid>>4)
  int jrow[8];
#pragma unroll
  for (int rd = 0; rd < 8; rd++) {
    int mm = m0 + rd * 16 + (tid >> 4);
    jrow[rd] = join[2 * (mm < N_FRAG ? mm : N_FRAG - 1) + 1];
  }

  auto stage = [&](int buf, int k0) {
#pragma unroll
    for (int jj = 0; jj < 2; jj++)
      async_copy16(Abase + (size_t)srow[jj] * K + k0 + skoff[jj], &sh[buf][ldsoff[jj]]);
#pragma unroll
    for (int jj = 0; jj < 2; jj++)
      async_copy16(Whhb + (size_t)brow[jj] * K + k0 + skoff[jj], &sh[3 + buf][ldsoff[jj]]);
  };

  f32x4 acc[4][4];
#pragma unroll
  for (int i = 0; i < 4; i++)
#pragma unroll
    for (int j = 0; j < 4; j++) acc[i][j] = (f32x4){0.f, 0.f, 0.f, 0.f};

  constexpr int nK = K / 32;        // 8
  stage(0, 0);
  stage(1, 32);
#pragma unroll
  for (int t = 0; t < nK; ++t) {
    if (t < nK - 1) __builtin_amdgcn_s_waitcnt(0xF74);  // vmcnt(4)
    else            __builtin_amdgcn_s_waitcnt(0xF70);  // vmcnt(0)
    __builtin_amdgcn_s_barrier();
    if (t + 2 < nK) stage((t + 2) % 3, (t + 2) * 32);
    const int buf = t % 3;
    bf16x8 af[4], bfr[4];
#pragma unroll
    for (int i = 0; i < 4; i++) {
      int m = wm + i * 16 + l16;
      int jp = quad ^ ((m >> 1) & 3);
      af[i] = *(const bf16x8*)&sh[buf][m * 32 + jp * 8];
    }
#pragma unroll
    for (int j = 0; j < 4; j++) {
      int n = wn + j * 16 + l16;
      int jp = quad ^ ((n >> 1) & 3);
      bfr[j] = *(const bf16x8*)&sh[3 + buf][n * 32 + jp * 8];
    }
#pragma unroll
    for (int i = 0; i < 4; i++)
#pragma unroll
      for (int j = 0; j < 4; j++)
        acc[i][j] = __builtin_amdgcn_mfma_f32_16x16x32_bf16(af[i], bfr[j], acc[i][j], 0, 0, 0);
  }

  // ---- fused LSTM step-2 epilogue ----
  __builtin_amdgcn_s_barrier();     // all waves done reading K-loop LDS
  // c1 prefetch: per (i,r) 16 lanes read a 32-B segment (independent)
  const int u_ = wnq * 16 + l16;
  u16 c1r[4][4];
#pragma unroll
  for (int i = 0; i < 4; i++)
#pragma unroll
    for (int r = 0; r < 4; r++) {
      int m = m0 + wm + i * 16 + quad * 4 + r;
      c1r[i][r] = c1in[(size_t)m * 256 + nstrip * 32 + u_];
    }
  // cooperative P[j1] stage: Pl[mloc][gate][4 chunks(swz) of 8 units]
  u16* Pl = &sh[0][0];              // 32 KiB
  {
    const int g = (tid >> 2) & 3;
    const int chunk = tid & 3;
#pragma unroll
    for (int rd = 0; rd < 8; rd++) {
      const int mloc = rd * 16 + (tid >> 4);
      const int cphys = chunk ^ ((mloc >> 2) & 3);
      async_copy16(P + (size_t)jrow[rd] * 1024 + g * 256 + nstrip * 32 + cphys * 8,
                   &Pl[(size_t)(rd * 256 + (tid & ~63)) * 8]);
    }
  }
  __builtin_amdgcn_s_waitcnt(0xF70);  // vmcnt(0): stage + c1 landed
  __builtin_amdgcn_s_barrier();
  __builtin_amdgcn_sched_barrier(0);

#pragma unroll
  for (int i = 0; i < 4; i++) {
#pragma unroll
    for (int r = 0; r < 4; r++) {
      const int mloc = wm + i * 16 + quad * 4 + r;
      const int m = m0 + mloc;
      const int base = (mloc * 16 + ((u_ >> 3) ^ ((mloc >> 2) & 3))) * 8 + (u_ & 7);
      float gi = acc[i][0][r] + bf2f(Pl[base]);
      float gf = acc[i][1][r] + bf2f(Pl[base + 32]);
      float gg = acc[i][2][r] + bf2f(Pl[base + 64]);
      float go = acc[i][3][r] + bf2f(Pl[base + 96]);
      float c1v = bf2f(c1r[i][r]);
      float cv = sigmoidf(gf) * c1v + sigmoidf(gi) * fast_tanh(gg);
      float hv = sigmoidf(go) * fast_tanh(cv);
      h2s[(size_t)m * 256 + nstrip * 32 + u_] = f2bf(hv);
    }
  }
}

// ------- K5: attention over {h1,h2} + output head (logits in-kernel) ------
__global__ __launch_bounds__(256) void lstm_attn_out(
    const u16* __restrict__ h1, const u16* __restrict__ h2s,
    const float* __restrict__ Wg, const float* __restrict__ Wout,
    const float* __restrict__ bout, float* __restrict__ frag_out) {
  int wave = threadIdx.x >> 6, lane = threadIdx.x & 63;
  int m = blockIdx.x * 4 + wave;
  if (m >= N_FRAG) return;
  ushort4 h1v = *(const ushort4*)(h1 + (size_t)m * 256 + lane * 4);
  ushort4 h2v = *(const ushort4*)(h2s + (size_t)m * 256 + lane * 4);
  float4 wg = *(const float4*)(Wg + lane * 4);
  const u16* h1p = (const u16*)&h1v;
  const u16* h2p = (const u16*)&h2v;
  const float* wgp = (const float*)&wg;

  float p1 = 0.f, p2 = 0.f;
#pragma unroll
  for (int k = 0; k < 4; k++) {
    p1 += bf2f(h1p[k]) * wgp[k];
    p2 += bf2f(h2p[k]) * wgp[k];
  }
#pragma unroll
  for (int off = 32; off; off >>= 1) {
    p1 += __shfl_xor(p1, off);
    p2 += __shfl_xor(p2, off);
  }
  float mx = fmaxf(p1, p2);
  float e1 = __expf(p1 - mx), e2 = __expf(p2 - mx);
  float inv = __frcp_rn(e1 + e2);
  float a1 = e1 * inv, a2 = e2 * inv;

  float acc[8];
#pragma unroll
  for (int t = 0; t < 8; t++) acc[t] = 0.f;
#pragma unroll
  for (int k = 0; k < 4; k++) {
    float frag = a1 * bf2f(h1p[k]) + a2 * bf2f(h2p[k]);
    int h = lane * 4 + k;
    float4 w0 = *(const float4*)(Wout + h * 8);
    float4 w1 = *(const float4*)(Wout + h * 8 + 4);
    acc[0] += frag * w0.x; acc[1] += frag * w0.y;
    acc[2] += frag * w0.z; acc[3] += frag * w0.w;
    acc[4] += frag * w1.x; acc[5] += frag * w1.y;
    acc[6] += frag * w1.z; acc[7] += frag * w1.w;
  }
#pragma unroll
  for (int off = 32; off; off >>= 1)
#pragma unroll
    for (int t = 0; t < 8; t++) acc[t] += __shfl_xor(acc[t], off);
  if (lane == 0) {
    float4 o0, o1;
    o0.x = fmaxf(acc[0] + bout[0], 0.f);
    o0.y = fmaxf(acc[1] + bout[1], 0.f);
    o0.z = fmaxf(acc[2] + bout[2], 0.f);
    o0.w = fmaxf(acc[3] + bout[3], 0.f);
    o1.x = fmaxf(acc[4] + bout[4], 0.f);
    o1.y = fmaxf(acc[5] + bout[5], 0.f);
    o1.z = fmaxf(acc[6] + bout[6], 0.f);
    o1.w = fmaxf(acc[7] + bout[7], 0.f);
    *(float4*)(frag_out + (size_t)m * 8) = o0;
    *(float4*)(frag_out + (size_t)m * 8 + 4) = o1;
  }
}

// ---------------- K6: combine scatter-sum ---------------------------------
__global__ __launch_bounds__(256) void scatter_sum(
    const float* __restrict__ frag_out, const int* __restrict__ comb,
    float* __restrict__ out) {
  int tid = blockIdx.x * 256 + threadIdx.x;
  if (tid >= N_OUT * 8) return;
  int n = tid >> 3, t = tid & 7;
  float s = 0.f;
#pragma unroll
  for (int d = 0; d < 4; d++) {
    int f = comb[n * 4 + d];
    s += frag_out[(size_t)f * 8 + t];
  }
  out[tid] = s;
}

extern "C" void kernel_launch(void* const* d_in, const int* in_sizes, int n_in,
                              void* d_out, int out_size, void* d_ws, size_t ws_size,
                              hipStream_t stream) {
  const float* feature = (const float*)d_in[0];
  const float* WgL = (const float*)d_in[1];
  const float* WgR = (const float*)d_in[2];
  const float* Wih = (const float*)d_in[3];
  const float* Whh = (const float*)d_in[4];
  const float* bih = (const float*)d_in[5];
  const float* bhh = (const float*)d_in[6];
  const float* Wgf = (const float*)d_in[7];
  const float* Wout = (const float*)d_in[8];
  const float* bout = (const float*)d_in[9];
  const int* lostS = (const int*)d_in[10];
  const int* retS = (const int*)d_in[11];
  const int* joinS = (const int*)d_in[12];
  const int* combS = (const int*)d_in[13];
  float* out = (float*)d_out;

  char* ws = (char*)d_ws;
  size_t off = 0;
  auto alloc = [&](size_t bytes) -> char* {
    char* p = ws + off;
    off = (off + bytes + 255) & ~(size_t)255;
    return p;
  };
  u16* Wihb = (u16*)alloc((size_t)1024 * 512 * 2);
  u16* Whhb = (u16*)alloc((size_t)1024 * 256 * 2);
  float* bias = (float*)alloc(1024 * 4);
  u16* P = (u16*)alloc((size_t)M_CLEAV_PAD * 1024 * 2);
  u16* h1 = (u16*)alloc((size_t)N_FRAG_PAD * 256 * 2);
  u16* c1 = (u16*)alloc((size_t)N_FRAG_PAD * 256 * 2);
  u16* h2s = (u16*)alloc((size_t)N_FRAG_PAD * 256 * 2);
  float* frag_out = (float*)alloc((size_t)N_FRAG * 8 * 4);
  u16* cleav = (u16*)alloc((size_t)M_CLEAV_PAD * 512 * 2);
  // featb (76.8 MB) + glog (1.2 MB) alias the P region: dead once
  // attn_pull2 completes, before GEMM-1 writes P (stream-ordered).
  u16* featb = P;
  float* glog = (float*)(P + (size_t)N_MONO * F);

  feat_prep<<<(N_MONO + 3) / 4, 256, 0, stream>>>(
      feature, WgL, WgR, featb, glog, Wih, Whh, bih, bhh, Wihb, Whhb, bias);
  attn_pull2<<<N_CLEAV / 4, 256, 0, stream>>>(featb, glog, lostS, retS, cleav);
  // GEMM-1: M=100352 = 448*224 strips, 56/XCD, 1792 blocks = 7/CU exact
  gemm224<<<1792, 512, 0, stream>>>(cleav, Wihb, P, bias, 56, 448);
  lstm_step1<<<N_FRAG_PAD / 4, 256, 0, stream>>>(P, joinS, h1, c1);
  // G2 fused: 626 mstrips x 8 nstrips = 5008 blocks, 3 blocks/CU resident
  g2fuse<<<626 * 8, 256, 0, stream>>>(h1, Whhb, P, joinS, c1, h2s);
  lstm_attn_out<<<N_FRAG / 4, 256, 0, stream>>>(
      h1, h2s, Wgf, Wout, bout, frag_out);
  scatter_sum<<<(N_OUT * 8 + 255) / 256, 256, 0, stream>>>(frag_out, combS, out);
}

// Round 8
// 657.815 us; speedup vs baseline: 1.1738x; 1.0503x over previous
//
#include <hip/hip_runtime.h>

typedef unsigned short u16;
typedef unsigned int u32;
typedef float f32x4 __attribute__((ext_vector_type(4)));
typedef __bf16 bf16x8 __attribute__((ext_vector_type(8)));

#define F 256
#define T_OUT 8
#define N_MONO 150000
#define N_CLEAV 100000
#define N_FRAG 80000
#define N_FRAG_PAD 80128     // 626 * 128
#define N_OUT 40000
#define M_CLEAV_PAD 100352   // 448 * 224

static __device__ __forceinline__ u16 f2bf(float f) {
  u32 u = __float_as_uint(f);
  u32 r = (u + 0x7FFFu + ((u >> 16) & 1u)) >> 16;
  return (u16)r;
}
static __device__ __forceinline__ float bf2f(u16 b) {
  return __uint_as_float(((u32)b) << 16);
}
static __device__ __forceinline__ float sigmoidf(float x) {
  return __frcp_rn(1.0f + __expf(-x));
}
static __device__ __forceinline__ float fast_tanh(float x) {
  return 1.0f - 2.0f * __frcp_rn(__expf(2.0f * x) + 1.0f);
}
static __device__ __forceinline__ void async_copy16(const u16* g, const u16* l) {
  __builtin_amdgcn_global_load_lds(
      (const __attribute__((address_space(1))) u32*)g,
      (__attribute__((address_space(3))) u32*)l,
      16, 0, 0);
}

// ---------------- K0a: weight cast + bias sum ----------------
__global__ __launch_bounds__(256) void prep_kernel(
    const float* __restrict__ Wih, const float* __restrict__ Whh,
    const float* __restrict__ bih, const float* __restrict__ bhh,
    u16* __restrict__ Wihb, u16* __restrict__ Whhb, float* __restrict__ bias) {
  int i = blockIdx.x * 256 + threadIdx.x;
  if (i < 1024 * 512) Wihb[i] = f2bf(Wih[i]);
  if (i < 1024 * 256) Whhb[i] = f2bf(Whh[i]);
  if (i < 1024) bias[i] = bih[i] + bhh[i];
}

// ------- K0b: feature bf16 copy + per-mono gate logits --------
__global__ __launch_bounds__(256) void feat_prep(
    const float* __restrict__ feat, const float* __restrict__ WgL,
    const float* __restrict__ WgR, u16* __restrict__ featb,
    float* __restrict__ glog) {
  int wave = threadIdx.x >> 6, lane = threadIdx.x & 63;
  int n = blockIdx.x * 4 + wave;
  if (n >= N_MONO) return;
  float4 x = *(const float4*)(feat + (size_t)n * F + lane * 4);
  u32 lo = (u32)f2bf(x.x) | ((u32)f2bf(x.y) << 16);
  u32 hi = (u32)f2bf(x.z) | ((u32)f2bf(x.w) << 16);
  *(uint2*)(featb + (size_t)n * F + lane * 4) = make_uint2(lo, hi);
  float4 wl = *(const float4*)(WgL + lane * 4);
  float4 wr = *(const float4*)(WgR + lane * 4);
  float pl = x.x * wl.x + x.y * wl.y + x.z * wl.z + x.w * wl.w;
  float pr = x.x * wr.x + x.y * wr.y + x.z * wr.z + x.w * wr.w;
#pragma unroll
  for (int off = 32; off; off >>= 1) {
    pl += __shfl_xor(pl, off);
    pr += __shfl_xor(pr, off);
  }
  if (lane == 0) {
    glog[n * 2] = pl;
    glog[n * 2 + 1] = pr;
  }
}

// ---------------- K1: attention pulls -> cleav [N_CLEAV, 512] bf16 --------
__global__ __launch_bounds__(256) void attn_pull2(
    const u16* __restrict__ featb, const float* __restrict__ glog,
    const int* __restrict__ lostS, const int* __restrict__ retS,
    u16* __restrict__ cleav) {
  int wave = threadIdx.x >> 6, lane = threadIdx.x & 63;
  int n = blockIdx.x * 4 + wave;
  if (n >= N_CLEAV) return;
#pragma unroll
  for (int sg = 0; sg < 2; ++sg) {
    const int* src = sg ? retS : lostS;
    int4 ridx = *(const int4*)(src + n * 4);
    int r[4] = {ridx.x, ridx.y, ridx.z, ridx.w};
    ushort4 x4[4];
    float lg[4];
#pragma unroll
    for (int d = 0; d < 4; ++d) {
      x4[d] = *(const ushort4*)(featb + (size_t)r[d] * F + lane * 4);
      lg[d] = glog[r[d] * 2 + sg];
    }
    float mx = fmaxf(fmaxf(lg[0], lg[1]), fmaxf(lg[2], lg[3]));
    float e0 = __expf(lg[0] - mx), e1 = __expf(lg[1] - mx);
    float e2 = __expf(lg[2] - mx), e3 = __expf(lg[3] - mx);
    float inv = __frcp_rn(e0 + e1 + e2 + e3);
    float a[4] = {e0 * inv, e1 * inv, e2 * inv, e3 * inv};
    float acc[4] = {0.f, 0.f, 0.f, 0.f};
#pragma unroll
    for (int d = 0; d < 4; ++d) {
      const u16* xp = (const u16*)&x4[d];
#pragma unroll
      for (int k = 0; k < 4; k++) acc[k] += a[d] * bf2f(xp[k]);
    }
    u32 lo = (u32)f2bf(acc[0]) | ((u32)f2bf(acc[1]) << 16);
    u32 hi = (u32)f2bf(acc[2]) | ((u32)f2bf(acc[3]) << 16);
    *(uint2*)(cleav + (size_t)n * 512 + sg * 256 + lane * 4) = make_uint2(lo, hi);
  }
}

// ---------------- GEMM-1: P = cleav @ Wih^T + bias (round-3 verified) -----
// BM=224 x 256 tile, BK=64, 8 waves, 4-phase double-buffered, vmcnt(4).
__global__ __launch_bounds__(512, 2) void gemm224(
    const u16* __restrict__ A, const u16* __restrict__ Bw,
    u16* __restrict__ C, const float* __restrict__ bias,
    int nper, int mstrips_valid) {
  constexpr int K = 512, BM = 224;
  constexpr int AREG = BM * 64;
  constexpr int BSZ = AREG + 16384;
  constexpr int WMH = BM / 2;
  constexpr int IB = BM / 32;            // 7
  constexpr int IB_HI = IB - 4;          // 3
  __shared__ u16 sh[2][BSZ];
  const int flat = blockIdx.x;
  const int xcd = flat & 7;
  const int w = flat >> 3;
  const int mstrip = xcd * nper + (w >> 2);
  const int nstrip = w & 3;
  if (mstrip >= mstrips_valid) return;
  const int m0 = mstrip * BM;
  const int n0 = nstrip * 256;

  const int tid = threadIdx.x;
  const int lane = tid & 63;
  const int wave = tid >> 6;
  const int quad = lane >> 4;
  const int l16 = lane & 15;
  const int s7 = l16 & 7;
  const int wm2 = wave >> 2;
  const int wn4 = wave & 3;

  const int arow = (wm2 * WMH + l16) * 64;
  const int brow = AREG + (wn4 * 64 + l16) * 64;
  const int coff0 = (quad ^ s7) * 8;
  const int coff1 = ((4 + quad) ^ s7) * 8;

  int sr[4], sw[4], dwv[4];
#pragma unroll
  for (int r = 0; r < 4; r++) {
    int c = r * 512 + tid;
    sr[r] = c >> 3;
    sw[r] = ((c & 7) ^ ((c >> 3) & 7)) * 8;
    dwv[r] = (r * 512 + (tid & ~63)) * 8;
  }
  const u16* Abase = A + (size_t)m0 * K;
  const u16* Bbase = Bw + (size_t)n0 * K;

  auto stageA = [&](int buf, int kt, int h) {
#pragma unroll
    for (int rr = 0; rr < 2; rr++) {
      int r = 2 * h + rr;
      if (r * 512 + tid < BM * 8)
        async_copy16(Abase + (size_t)sr[r] * K + kt * 64 + sw[r], &sh[buf][dwv[r]]);
    }
  };
  auto stageB = [&](int buf, int kt, int h) {
#pragma unroll
    for (int rr = 0; rr < 2; rr++) {
      int r = 2 * h + rr;
      async_copy16(Bbase + (size_t)sr[r] * K + kt * 64 + sw[r], &sh[buf][AREG + dwv[r]]);
    }
  };

  f32x4 acc[IB][4];
#pragma unroll
  for (int i = 0; i < IB; i++)
#pragma unroll
    for (int j = 0; j < 4; j++) acc[i][j] = (f32x4){0.f, 0.f, 0.f, 0.f};

  constexpr int nK = K / 64;
  stageA(0, 0, 0); stageA(0, 0, 1); stageB(0, 0, 0); stageB(0, 0, 1);
  stageB(1, 1, 0); stageB(1, 1, 1);
  __builtin_amdgcn_s_waitcnt(0xF74);
  __builtin_amdgcn_s_barrier();

  bf16x8 a[4][2], b0[2][2], b1[2][2];
#pragma unroll
  for (int t = 0; t < nK; ++t) {
    const int bsel = t & 1;
    const u16* S = &sh[bsel][0];

#pragma unroll
    for (int i = 0; i < 4; i++) {
      a[i][0] = *(const bf16x8*)&S[arow + i * 1024 + coff0];
      a[i][1] = *(const bf16x8*)&S[arow + i * 1024 + coff1];
    }
#pragma unroll
    for (int j = 0; j < 2; j++) {
      b0[j][0] = *(const bf16x8*)&S[brow + j * 1024 + coff0];
      b0[j][1] = *(const bf16x8*)&S[brow + j * 1024 + coff1];
    }
    if (t + 1 < nK) stageA(bsel ^ 1, t + 1, 0);
    __builtin_amdgcn_s_waitcnt(0xC87F);
    __builtin_amdgcn_s_barrier();
    __builtin_amdgcn_s_waitcnt(0xC07F);
    __builtin_amdgcn_sched_barrier(0);
    __builtin_amdgcn_s_setprio(1);
#pragma unroll
    for (int i = 0; i < 4; i++)
#pragma unroll
      for (int j = 0; j < 2; j++) {
        acc[i][j] = __builtin_amdgcn_mfma_f32_16x16x32_bf16(a[i][0], b0[j][0], acc[i][j], 0, 0, 0);
        acc[i][j] = __builtin_amdgcn_mfma_f32_16x16x32_bf16(a[i][1], b0[j][1], acc[i][j], 0, 0, 0);
      }
    __builtin_amdgcn_s_setprio(0);
    __builtin_amdgcn_s_barrier();

#pragma unroll
    for (int j = 0; j < 2; j++) {
      b1[j][0] = *(const bf16x8*)&S[brow + (2 + j) * 1024 + coff0];
      b1[j][1] = *(const bf16x8*)&S[brow + (2 + j) * 1024 + coff1];
    }
    if (t + 1 < nK) stageA(bsel ^ 1, t + 1, 1);
    __builtin_amdgcn_s_barrier();
    __builtin_amdgcn_s_waitcnt(0xC07F);
    __builtin_amdgcn_sched_barrier(0);
    __builtin_amdgcn_s_setprio(1);
#pragma unroll
    for (int i = 0; i < 4; i++)
#pragma unroll
      for (int j = 0; j < 2; j++) {
        acc[i][2 + j] = __builtin_amdgcn_mfma_f32_16x16x32_bf16(a[i][0], b1[j][0], acc[i][2 + j], 0, 0, 0);
        acc[i][2 + j] = __builtin_amdgcn_mfma_f32_16x16x32_bf16(a[i][1], b1[j][1], acc[i][2 + j], 0, 0, 0);
      }
    __builtin_amdgcn_s_setprio(0);
    __builtin_amdgcn_s_barrier();

#pragma unroll
    for (int i = 0; i < IB_HI; i++) {
      a[i][0] = *(const bf16x8*)&S[arow + (4 + i) * 1024 + coff0];
      a[i][1] = *(const bf16x8*)&S[arow + (4 + i) * 1024 + coff1];
    }
    if (t + 2 < nK) stageB(bsel, t + 2, 0);
    __builtin_amdgcn_s_barrier();
    __builtin_amdgcn_s_waitcnt(0xC07F);
    __builtin_amdgcn_sched_barrier(0);
    __builtin_amdgcn_s_setprio(1);
#pragma unroll
    for (int i = 0; i < IB_HI; i++)
#pragma unroll
      for (int j = 0; j < 2; j++) {
        acc[4 + i][j] = __builtin_amdgcn_mfma_f32_16x16x32_bf16(a[i][0], b0[j][0], acc[4 + i][j], 0, 0, 0);
        acc[4 + i][j] = __builtin_amdgcn_mfma_f32_16x16x32_bf16(a[i][1], b0[j][1], acc[4 + i][j], 0, 0, 0);
      }
    __builtin_amdgcn_s_setprio(0);
    __builtin_amdgcn_s_barrier();

    if (t + 2 < nK) stageB(bsel, t + 2, 1);
    __builtin_amdgcn_s_barrier();
    __builtin_amdgcn_s_setprio(1);
#pragma unroll
    for (int i = 0; i < IB_HI; i++)
#pragma unroll
      for (int j = 0; j < 2; j++) {
        acc[4 + i][2 + j] = __builtin_amdgcn_mfma_f32_16x16x32_bf16(a[i][0], b1[j][0], acc[4 + i][2 + j], 0, 0, 0);
        acc[4 + i][2 + j] = __builtin_amdgcn_mfma_f32_16x16x32_bf16(a[i][1], b1[j][1], acc[4 + i][2 + j], 0, 0, 0);
      }
    __builtin_amdgcn_s_setprio(0);
    if (t + 2 < nK) __builtin_amdgcn_s_waitcnt(0xF74);
    else            __builtin_amdgcn_s_waitcnt(0xF70);
    __builtin_amdgcn_s_barrier();
  }

  float badd[4];
#pragma unroll
  for (int j = 0; j < 4; j++)
    badd[j] = bias[n0 + wn4 * 64 + j * 16 + l16];
#pragma unroll
  for (int i = 0; i < IB; i++) {
    const int mrow = m0 + wm2 * WMH + i * 16 + quad * 4;
#pragma unroll
    for (int j = 0; j < 4; j++) {
      const int n = n0 + wn4 * 64 + j * 16 + l16;
#pragma unroll
      for (int r = 0; r < 4; r++)
        C[(size_t)(mrow + r) * 1024 + n] = f2bf(acc[i][j][r] + badd[j]);
    }
  }
}

// ---------------- K3: LSTM step 1, wave-per-fragment ----------------------
// Zero-fills pad rows [N_FRAG, N_FRAG_PAD) so g2fuse reads defined data.
__global__ __launch_bounds__(256) void lstm_step1(
    const u16* __restrict__ P, const int* __restrict__ join,
    u16* __restrict__ h1, u16* __restrict__ c1) {
  int wave = threadIdx.x >> 6, lane = threadIdx.x & 63;
  int m = blockIdx.x * 4 + wave;
  if (m >= N_FRAG_PAD) return;
  if (m >= N_FRAG) {
    *(ushort4*)(h1 + (size_t)m * 256 + lane * 4) = make_ushort4(0, 0, 0, 0);
    *(ushort4*)(c1 + (size_t)m * 256 + lane * 4) = make_ushort4(0, 0, 0, 0);
    return;
  }
  int j0 = join[2 * m];
  const u16* row = P + (size_t)j0 * 1024 + lane * 4;
  ushort4 iv = *(const ushort4*)(row);
  ushort4 gv = *(const ushort4*)(row + 512);
  ushort4 ov = *(const ushort4*)(row + 768);
  const u16* ivp = (const u16*)&iv;
  const u16* gvp = (const u16*)&gv;
  const u16* ovp = (const u16*)&ov;
  ushort4 h4, c4;
  u16* h4p = (u16*)&h4;
  u16* c4p = (u16*)&c4;
#pragma unroll
  for (int k = 0; k < 4; k++) {
    float c = sigmoidf(bf2f(ivp[k])) * fast_tanh(bf2f(gvp[k]));
    float hv = sigmoidf(bf2f(ovp[k])) * fast_tanh(c);
    h4p[k] = f2bf(hv);
    c4p[k] = f2bf(c);
  }
  *(ushort4*)(h1 + (size_t)m * 256 + lane * 4) = h4;
  *(ushort4*)(c1 + (size_t)m * 256 + lane * 4) = c4;
}

// ------- G2 fused: gates2 = h1 @ Whh^T (+P[j1], +c1) -> h2  ---------------
// 128x128 tile, BK=32, 256 thr, triple-buffered LDS (48 KiB, 3 blocks/CU).
// XCD-COLOCATED mapping: the 8 nstrip-blocks of each mstrip land on the
// SAME XCD (xcd = mstrip%8, blockIdx = k*8+xcd, nstrip = k&7), so the
// mstrip's shared h1 A-tile and gathered P[j1] rows are fetched into that
// XCD's L2 once and line-shared across all 8 gate/unit slices (the R7
// mapping put them on 8 different L2s -> ~2x P-gather line waste).
// Rest identical to R7's verified kernel.
__global__ __launch_bounds__(256, 3) void g2fuse(
    const u16* __restrict__ h1A, const u16* __restrict__ Whhb,
    const u16* __restrict__ P, const int* __restrict__ join,
    const u16* __restrict__ c1in, u16* __restrict__ h2s) {
  constexpr int K = 256;
  __shared__ u16 sh[6][128 * 32];   // A bufs 0-2, B bufs 3-5 (48 KiB)
  const int b = blockIdx.x;
  const int xcd = b & 7;
  const int k = b >> 3;             // 0..631
  const int nstrip = k & 7;
  const int mstrip = (k >> 3) * 8 + xcd;   // 0..631
  if (mstrip >= 626) return;
  const int m0 = mstrip * 128;

  const int tid = threadIdx.x;
  const int lane = tid & 63;
  const int wave = tid >> 6;
  const int quad = lane >> 4;
  const int l16 = lane & 15;
  const int wm = (wave & 1) * 64;
  const int wnq = wave >> 1;        // 0..1
  const int wn = wnq * 64;

  int srow[2], skoff[2], ldsoff[2], brow[2];
#pragma unroll
  for (int jj = 0; jj < 2; jj++) {
    int c = jj * 256 + tid;
    int row = c >> 2;
    srow[jj] = row;
    skoff[jj] = ((c & 3) ^ ((c >> 3) & 3)) * 8;
    ldsoff[jj] = (jj * 256 + (tid & ~63)) * 8;
    brow[jj] = ((row >> 4) & 3) * 256 + nstrip * 32 + ((row >> 6) << 4) + (row & 15);
  }
  const u16* Abase = h1A + (size_t)m0 * K;

  // j1 indices for the epilogue stage: round rd covers mloc = rd*16+(tid>>4)
  int jrow[8];
#pragma unroll
  for (int rd = 0; rd < 8; rd++) {
    int mm = m0 + rd * 16 + (tid >> 4);
    jrow[rd] = join[2 * (mm < N_FRAG ? mm : N_FRAG - 1) + 1];
  }

  auto stage = [&](int buf, int k0) {
#pragma unroll
    for (int jj = 0; jj < 2; jj++)
      async_copy16(Abase + (size_t)srow[jj] * K + k0 + skoff[jj], &sh[buf][ldsoff[jj]]);
#pragma unroll
    for (int jj = 0; jj < 2; jj++)
      async_copy16(Whhb + (size_t)brow[jj] * K + k0 + skoff[jj], &sh[3 + buf][ldsoff[jj]]);
  };

  f32x4 acc[4][4];
#pragma unroll
  for (int i = 0; i < 4; i++)
#pragma unroll
    for (int j = 0; j < 4; j++) acc[i][j] = (f32x4){0.f, 0.f, 0.f, 0.f};

  constexpr int nK = K / 32;        // 8
  stage(0, 0);
  stage(1, 32);
#pragma unroll
  for (int t = 0; t < nK; ++t) {
    if (t < nK - 1) __builtin_amdgcn_s_waitcnt(0xF74);  // vmcnt(4)
    else            __builtin_amdgcn_s_waitcnt(0xF70);  // vmcnt(0)
    __builtin_amdgcn_s_barrier();
    if (t + 2 < nK) stage((t + 2) % 3, (t + 2) * 32);
    const int buf = t % 3;
    bf16x8 af[4], bfr[4];
#pragma unroll
    for (int i = 0; i < 4; i++) {
      int m = wm + i * 16 + l16;
      int jp = quad ^ ((m >> 1) & 3);
      af[i] = *(const bf16x8*)&sh[buf][m * 32 + jp * 8];
    }
#pragma unroll
    for (int j = 0; j < 4; j++) {
      int n = wn + j * 16 + l16;
      int jp = quad ^ ((n >> 1) & 3);
      bfr[j] = *(const bf16x8*)&sh[3 + buf][n * 32 + jp * 8];
    }
#pragma unroll
    for (int i = 0; i < 4; i++)
#pragma unroll
      for (int j = 0; j < 4; j++)
        acc[i][j] = __builtin_amdgcn_mfma_f32_16x16x32_bf16(af[i], bfr[j], acc[i][j], 0, 0, 0);
  }

  // ---- fused LSTM step-2 epilogue ----
  __builtin_amdgcn_s_barrier();     // all waves done reading K-loop LDS
  const int u_ = wnq * 16 + l16;
  u16 c1r[4][4];
#pragma unroll
  for (int i = 0; i < 4; i++)
#pragma unroll
    for (int r = 0; r < 4; r++) {
      int m = m0 + wm + i * 16 + quad * 4 + r;
      c1r[i][r] = c1in[(size_t)m * 256 + nstrip * 32 + u_];
    }
  // cooperative P[j1] stage: Pl[mloc][gate][4 chunks(swz) of 8 units]
  u16* Pl = &sh[0][0];              // 32 KiB
  {
    const int g = (tid >> 2) & 3;
    const int chunk = tid & 3;
#pragma unroll
    for (int rd = 0; rd < 8; rd++) {
      const int mloc = rd * 16 + (tid >> 4);
      const int cphys = chunk ^ ((mloc >> 2) & 3);
      async_copy16(P + (size_t)jrow[rd] * 1024 + g * 256 + nstrip * 32 + cphys * 8,
                   &Pl[(size_t)(rd * 256 + (tid & ~63)) * 8]);
    }
  }
  __builtin_amdgcn_s_waitcnt(0xF70);  // vmcnt(0): stage + c1 landed
  __builtin_amdgcn_s_barrier();
  __builtin_amdgcn_sched_barrier(0);

#pragma unroll
  for (int i = 0; i < 4; i++) {
#pragma unroll
    for (int r = 0; r < 4; r++) {
      const int mloc = wm + i * 16 + quad * 4 + r;
      const int m = m0 + mloc;
      const int base = (mloc * 16 + ((u_ >> 3) ^ ((mloc >> 2) & 3))) * 8 + (u_ & 7);
      float gi = acc[i][0][r] + bf2f(Pl[base]);
      float gf = acc[i][1][r] + bf2f(Pl[base + 32]);
      float gg = acc[i][2][r] + bf2f(Pl[base + 64]);
      float go = acc[i][3][r] + bf2f(Pl[base + 96]);
      float c1v = bf2f(c1r[i][r]);
      float cv = sigmoidf(gf) * c1v + sigmoidf(gi) * fast_tanh(gg);
      float hv = sigmoidf(go) * fast_tanh(cv);
      h2s[(size_t)m * 256 + nstrip * 32 + u_] = f2bf(hv);
    }
  }
}

// ------- K5: attention over {h1,h2} + output head (logits in-kernel) ------
__global__ __launch_bounds__(256) void lstm_attn_out(
    const u16* __restrict__ h1, const u16* __restrict__ h2s,
    const float* __restrict__ Wg, const float* __restrict__ Wout,
    const float* __restrict__ bout, float* __restrict__ frag_out) {
  int wave = threadIdx.x >> 6, lane = threadIdx.x & 63;
  int m = blockIdx.x * 4 + wave;
  if (m >= N_FRAG) return;
  ushort4 h1v = *(const ushort4*)(h1 + (size_t)m * 256 + lane * 4);
  ushort4 h2v = *(const ushort4*)(h2s + (size_t)m * 256 + lane * 4);
  float4 wg = *(const float4*)(Wg + lane * 4);
  const u16* h1p = (const u16*)&h1v;
  const u16* h2p = (const u16*)&h2v;
  const float* wgp = (const float*)&wg;

  float p1 = 0.f, p2 = 0.f;
#pragma unroll
  for (int k = 0; k < 4; k++) {
    p1 += bf2f(h1p[k]) * wgp[k];
    p2 += bf2f(h2p[k]) * wgp[k];
  }
#pragma unroll
  for (int off = 32; off; off >>= 1) {
    p1 += __shfl_xor(p1, off);
    p2 += __shfl_xor(p2, off);
  }
  float mx = fmaxf(p1, p2);
  float e1 = __expf(p1 - mx), e2 = __expf(p2 - mx);
  float inv = __frcp_rn(e1 + e2);
  float a1 = e1 * inv, a2 = e2 * inv;

  float acc[8];
#pragma unroll
  for (int t = 0; t < 8; t++) acc[t] = 0.f;
#pragma unroll
  for (int k = 0; k < 4; k++) {
    float frag = a1 * bf2f(h1p[k]) + a2 * bf2f(h2p[k]);
    int h = lane * 4 + k;
    float4 w0 = *(const float4*)(Wout + h * 8);
    float4 w1 = *(const float4*)(Wout + h * 8 + 4);
    acc[0] += frag * w0.x; acc[1] += frag * w0.y;
    acc[2] += frag * w0.z; acc[3] += frag * w0.w;
    acc[4] += frag * w1.x; acc[5] += frag * w1.y;
    acc[6] += frag * w1.z; acc[7] += frag * w1.w;
  }
#pragma unroll
  for (int off = 32; off; off >>= 1)
#pragma unroll
    for (int t = 0; t < 8; t++) acc[t] += __shfl_xor(acc[t], off);
  if (lane == 0) {
    float4 o0, o1;
    o0.x = fmaxf(acc[0] + bout[0], 0.f);
    o0.y = fmaxf(acc[1] + bout[1], 0.f);
    o0.z = fmaxf(acc[2] + bout[2], 0.f);
    o0.w = fmaxf(acc[3] + bout[3], 0.f);
    o1.x = fmaxf(acc[4] + bout[4], 0.f);
    o1.y = fmaxf(acc[5] + bout[5], 0.f);
    o1.z = fmaxf(acc[6] + bout[6], 0.f);
    o1.w = fmaxf(acc[7] + bout[7], 0.f);
    *(float4*)(frag_out + (size_t)m * 8) = o0;
    *(float4*)(frag_out + (size_t)m * 8 + 4) = o1;
  }
}

// ---------------- K6: combine scatter-sum ---------------------------------
__global__ __launch_bounds__(256) void scatter_sum(
    const float* __restrict__ frag_out, const int* __restrict__ comb,
    float* __restrict__ out) {
  int tid = blockIdx.x * 256 + threadIdx.x;
  if (tid >= N_OUT * 8) return;
  int n = tid >> 3, t = tid & 7;
  float s = 0.f;
#pragma unroll
  for (int d = 0; d < 4; d++) {
    int f = comb[n * 4 + d];
    s += frag_out[(size_t)f * 8 + t];
  }
  out[tid] = s;
}

extern "C" void kernel_launch(void* const* d_in, const int* in_sizes, int n_in,
                              void* d_out, int out_size, void* d_ws, size_t ws_size,
                              hipStream_t stream) {
  const float* feature = (const float*)d_in[0];
  const float* WgL = (const float*)d_in[1];
  const float* WgR = (const float*)d_in[2];
  const float* Wih = (const float*)d_in[3];
  const float* Whh = (const float*)d_in[4];
  const float* bih = (const float*)d_in[5];
  const float* bhh = (const float*)d_in[6];
  const float* Wgf = (const float*)d_in[7];
  const float* Wout = (const float*)d_in[8];
  const float* bout = (const float*)d_in[9];
  const int* lostS = (const int*)d_in[10];
  const int* retS = (const int*)d_in[11];
  const int* joinS = (const int*)d_in[12];
  const int* combS = (const int*)d_in[13];
  float* out = (float*)d_out;

  char* ws = (char*)d_ws;
  size_t off = 0;
  auto alloc = [&](size_t bytes) -> char* {
    char* p = ws + off;
    off = (off + bytes + 255) & ~(size_t)255;
    return p;
  };
  u16* Wihb = (u16*)alloc((size_t)1024 * 512 * 2);
  u16* Whhb = (u16*)alloc((size_t)1024 * 256 * 2);
  float* bias = (float*)alloc(1024 * 4);
  u16* P = (u16*)alloc((size_t)M_CLEAV_PAD * 1024 * 2);
  u16* h1 = (u16*)alloc((size_t)N_FRAG_PAD * 256 * 2);
  u16* c1 = (u16*)alloc((size_t)N_FRAG_PAD * 256 * 2);
  u16* h2s = (u16*)alloc((size_t)N_FRAG_PAD * 256 * 2);
  float* frag_out = (float*)alloc((size_t)N_FRAG * 8 * 4);
  u16* cleav = (u16*)alloc((size_t)M_CLEAV_PAD * 512 * 2);
  // featb (76.8 MB) + glog (1.2 MB) alias the P region: dead once
  // attn_pull2 completes, before GEMM-1 writes P (stream-ordered).
  u16* featb = P;
  float* glog = (float*)(P + (size_t)N_MONO * F);

  prep_kernel<<<2048, 256, 0, stream>>>(Wih, Whh, bih, bhh, Wihb, Whhb, bias);
  feat_prep<<<(N_MONO + 3) / 4, 256, 0, stream>>>(feature, WgL, WgR, featb, glog);
  attn_pull2<<<N_CLEAV / 4, 256, 0, stream>>>(featb, glog, lostS, retS, cleav);
  // GEMM-1: M=100352 = 448*224 strips, 56/XCD, 1792 blocks = 7/CU exact
  gemm224<<<1792, 512, 0, stream>>>(cleav, Wihb, P, bias, 56, 448);
  lstm_step1<<<N_FRAG_PAD / 4, 256, 0, stream>>>(P, joinS, h1, c1);
  // G2 fused: 632 virtual mstrips (79/XCD) x 8 nstrips = 5056 blocks,
  // XCD-colocated (mstrip%8 = xcd); tail mstrips 626..631 early-exit.
  g2fuse<<<632 * 8, 256, 0, stream>>>(h1, Whhb, P, joinS, c1, h2s);
  lstm_attn_out<<<N_FRAG / 4, 256, 0, stream>>>(
      h1, h2s, Wgf, Wout, bout, frag_out);
  scatter_sum<<<(N_OUT * 8 + 255) / 256, 256, 0, stream>>>(frag_out, combS, out);
}

// Round 9
// 634.311 us; speedup vs baseline: 1.2173x; 1.0371x over previous
//
#include <hip/hip_runtime.h>

typedef unsigned short u16;
typedef unsigned int u32;
typedef float f32x4 __attribute__((ext_vector_type(4)));
typedef __bf16 bf16x8 __attribute__((ext_vector_type(8)));

#define F 256
#define T_OUT 8
#define N_MONO 150000
#define N_CLEAV 100000
#define N_FRAG 80000
#define N_FRAG_PAD 80128     // 626 * 128
#define N_OUT 40000
#define M_CLEAV_PAD 100352   // 448 * 224

static __device__ __forceinline__ u16 f2bf(float f) {
  u32 u = __float_as_uint(f);
  u32 r = (u + 0x7FFFu + ((u >> 16) & 1u)) >> 16;
  return (u16)r;
}
static __device__ __forceinline__ float bf2f(u16 b) {
  return __uint_as_float(((u32)b) << 16);
}
static __device__ __forceinline__ float sigmoidf(float x) {
  return __frcp_rn(1.0f + __expf(-x));
}
static __device__ __forceinline__ float fast_tanh(float x) {
  return 1.0f - 2.0f * __frcp_rn(__expf(2.0f * x) + 1.0f);
}
static __device__ __forceinline__ void async_copy16(const u16* g, const u16* l) {
  __builtin_amdgcn_global_load_lds(
      (const __attribute__((address_space(1))) u32*)g,
      (__attribute__((address_space(3))) u32*)l,
      16, 0, 0);
}

// ---------------- K0a: weight cast + bias sum ----------------
__global__ __launch_bounds__(256) void prep_kernel(
    const float* __restrict__ Wih, const float* __restrict__ Whh,
    const float* __restrict__ bih, const float* __restrict__ bhh,
    u16* __restrict__ Wihb, u16* __restrict__ Whhb, float* __restrict__ bias) {
  int i = blockIdx.x * 256 + threadIdx.x;
  if (i < 1024 * 512) Wihb[i] = f2bf(Wih[i]);
  if (i < 1024 * 256) Whhb[i] = f2bf(Whh[i]);
  if (i < 1024) bias[i] = bih[i] + bhh[i];
}

// ------- K0b: feature bf16 copy + per-mono gate logits --------
__global__ __launch_bounds__(256) void feat_prep(
    const float* __restrict__ feat, const float* __restrict__ WgL,
    const float* __restrict__ WgR, u16* __restrict__ featb,
    float* __restrict__ glog) {
  int wave = threadIdx.x >> 6, lane = threadIdx.x & 63;
  int n = blockIdx.x * 4 + wave;
  if (n >= N_MONO) return;
  float4 x = *(const float4*)(feat + (size_t)n * F + lane * 4);
  u32 lo = (u32)f2bf(x.x) | ((u32)f2bf(x.y) << 16);
  u32 hi = (u32)f2bf(x.z) | ((u32)f2bf(x.w) << 16);
  *(uint2*)(featb + (size_t)n * F + lane * 4) = make_uint2(lo, hi);
  float4 wl = *(const float4*)(WgL + lane * 4);
  float4 wr = *(const float4*)(WgR + lane * 4);
  float pl = x.x * wl.x + x.y * wl.y + x.z * wl.z + x.w * wl.w;
  float pr = x.x * wr.x + x.y * wr.y + x.z * wr.z + x.w * wr.w;
#pragma unroll
  for (int off = 32; off; off >>= 1) {
    pl += __shfl_xor(pl, off);
    pr += __shfl_xor(pr, off);
  }
  if (lane == 0) {
    glog[n * 2] = pl;
    glog[n * 2 + 1] = pr;
  }
}

// ---------------- K1: attention pulls -> cleav [N_CLEAV, 512] bf16 --------
// TWO cleavages per wave: all 32 loads (16 rows + 16 logits) issued before
// any compute -> 2x memory-level parallelism for the latency-bound gather.
__global__ __launch_bounds__(256) void attn_pull2(
    const u16* __restrict__ featb, const float* __restrict__ glog,
    const int* __restrict__ lostS, const int* __restrict__ retS,
    u16* __restrict__ cleav) {
  int wave = threadIdx.x >> 6, lane = threadIdx.x & 63;
  int n0 = blockIdx.x * 8 + wave * 2;
  if (n0 >= N_CLEAV) return;
  int r[2][2][4];
#pragma unroll
  for (int c = 0; c < 2; ++c) {
    int4 rl = *(const int4*)(lostS + (n0 + c) * 4);
    int4 rr = *(const int4*)(retS + (n0 + c) * 4);
    r[c][0][0] = rl.x; r[c][0][1] = rl.y; r[c][0][2] = rl.z; r[c][0][3] = rl.w;
    r[c][1][0] = rr.x; r[c][1][1] = rr.y; r[c][1][2] = rr.z; r[c][1][3] = rr.w;
  }
  ushort4 x4[2][2][4];
  float lg[2][2][4];
#pragma unroll
  for (int c = 0; c < 2; ++c)
#pragma unroll
    for (int sg = 0; sg < 2; ++sg)
#pragma unroll
      for (int d = 0; d < 4; ++d) {
        x4[c][sg][d] = *(const ushort4*)(featb + (size_t)r[c][sg][d] * F + lane * 4);
        lg[c][sg][d] = glog[r[c][sg][d] * 2 + sg];
      }
#pragma unroll
  for (int c = 0; c < 2; ++c)
#pragma unroll
    for (int sg = 0; sg < 2; ++sg) {
      float l0 = lg[c][sg][0], l1 = lg[c][sg][1];
      float l2 = lg[c][sg][2], l3 = lg[c][sg][3];
      float mx = fmaxf(fmaxf(l0, l1), fmaxf(l2, l3));
      float e0 = __expf(l0 - mx), e1 = __expf(l1 - mx);
      float e2 = __expf(l2 - mx), e3 = __expf(l3 - mx);
      float inv = __frcp_rn(e0 + e1 + e2 + e3);
      float a[4] = {e0 * inv, e1 * inv, e2 * inv, e3 * inv};
      float acc[4] = {0.f, 0.f, 0.f, 0.f};
#pragma unroll
      for (int d = 0; d < 4; ++d) {
        const u16* xp = (const u16*)&x4[c][sg][d];
#pragma unroll
        for (int k = 0; k < 4; k++) acc[k] += a[d] * bf2f(xp[k]);
      }
      u32 lo = (u32)f2bf(acc[0]) | ((u32)f2bf(acc[1]) << 16);
      u32 hi = (u32)f2bf(acc[2]) | ((u32)f2bf(acc[3]) << 16);
      *(uint2*)(cleav + (size_t)(n0 + c) * 512 + sg * 256 + lane * 4) =
          make_uint2(lo, hi);
    }
}

// ---------------- GEMM-1: P = cleav @ Wih^T + bias (round-3 verified) -----
// BM=224 x 256 tile, BK=64, 8 waves, 4-phase double-buffered, vmcnt(4).
__global__ __launch_bounds__(512, 2) void gemm224(
    const u16* __restrict__ A, const u16* __restrict__ Bw,
    u16* __restrict__ C, const float* __restrict__ bias,
    int nper, int mstrips_valid) {
  constexpr int K = 512, BM = 224;
  constexpr int AREG = BM * 64;
  constexpr int BSZ = AREG + 16384;
  constexpr int WMH = BM / 2;
  constexpr int IB = BM / 32;            // 7
  constexpr int IB_HI = IB - 4;          // 3
  __shared__ u16 sh[2][BSZ];
  const int flat = blockIdx.x;
  const int xcd = flat & 7;
  const int w = flat >> 3;
  const int mstrip = xcd * nper + (w >> 2);
  const int nstrip = w & 3;
  if (mstrip >= mstrips_valid) return;
  const int m0 = mstrip * BM;
  const int n0 = nstrip * 256;

  const int tid = threadIdx.x;
  const int lane = tid & 63;
  const int wave = tid >> 6;
  const int quad = lane >> 4;
  const int l16 = lane & 15;
  const int s7 = l16 & 7;
  const int wm2 = wave >> 2;
  const int wn4 = wave & 3;

  const int arow = (wm2 * WMH + l16) * 64;
  const int brow = AREG + (wn4 * 64 + l16) * 64;
  const int coff0 = (quad ^ s7) * 8;
  const int coff1 = ((4 + quad) ^ s7) * 8;

  int sr[4], sw[4], dwv[4];
#pragma unroll
  for (int r = 0; r < 4; r++) {
    int c = r * 512 + tid;
    sr[r] = c >> 3;
    sw[r] = ((c & 7) ^ ((c >> 3) & 7)) * 8;
    dwv[r] = (r * 512 + (tid & ~63)) * 8;
  }
  const u16* Abase = A + (size_t)m0 * K;
  const u16* Bbase = Bw + (size_t)n0 * K;

  auto stageA = [&](int buf, int kt, int h) {
#pragma unroll
    for (int rr = 0; rr < 2; rr++) {
      int r = 2 * h + rr;
      if (r * 512 + tid < BM * 8)
        async_copy16(Abase + (size_t)sr[r] * K + kt * 64 + sw[r], &sh[buf][dwv[r]]);
    }
  };
  auto stageB = [&](int buf, int kt, int h) {
#pragma unroll
    for (int rr = 0; rr < 2; rr++) {
      int r = 2 * h + rr;
      async_copy16(Bbase + (size_t)sr[r] * K + kt * 64 + sw[r], &sh[buf][AREG + dwv[r]]);
    }
  };

  f32x4 acc[IB][4];
#pragma unroll
  for (int i = 0; i < IB; i++)
#pragma unroll
    for (int j = 0; j < 4; j++) acc[i][j] = (f32x4){0.f, 0.f, 0.f, 0.f};

  constexpr int nK = K / 64;
  stageA(0, 0, 0); stageA(0, 0, 1); stageB(0, 0, 0); stageB(0, 0, 1);
  stageB(1, 1, 0); stageB(1, 1, 1);
  __builtin_amdgcn_s_waitcnt(0xF74);
  __builtin_amdgcn_s_barrier();

  bf16x8 a[4][2], b0[2][2], b1[2][2];
#pragma unroll
  for (int t = 0; t < nK; ++t) {
    const int bsel = t & 1;
    const u16* S = &sh[bsel][0];

#pragma unroll
    for (int i = 0; i < 4; i++) {
      a[i][0] = *(const bf16x8*)&S[arow + i * 1024 + coff0];
      a[i][1] = *(const bf16x8*)&S[arow + i * 1024 + coff1];
    }
#pragma unroll
    for (int j = 0; j < 2; j++) {
      b0[j][0] = *(const bf16x8*)&S[brow + j * 1024 + coff0];
      b0[j][1] = *(const bf16x8*)&S[brow + j * 1024 + coff1];
    }
    if (t + 1 < nK) stageA(bsel ^ 1, t + 1, 0);
    __builtin_amdgcn_s_waitcnt(0xC87F);
    __builtin_amdgcn_s_barrier();
    __builtin_amdgcn_s_waitcnt(0xC07F);
    __builtin_amdgcn_sched_barrier(0);
    __builtin_amdgcn_s_setprio(1);
#pragma unroll
    for (int i = 0; i < 4; i++)
#pragma unroll
      for (int j = 0; j < 2; j++) {
        acc[i][j] = __builtin_amdgcn_mfma_f32_16x16x32_bf16(a[i][0], b0[j][0], acc[i][j], 0, 0, 0);
        acc[i][j] = __builtin_amdgcn_mfma_f32_16x16x32_bf16(a[i][1], b0[j][1], acc[i][j], 0, 0, 0);
      }
    __builtin_amdgcn_s_setprio(0);
    __builtin_amdgcn_s_barrier();

#pragma unroll
    for (int j = 0; j < 2; j++) {
      b1[j][0] = *(const bf16x8*)&S[brow + (2 + j) * 1024 + coff0];
      b1[j][1] = *(const bf16x8*)&S[brow + (2 + j) * 1024 + coff1];
    }
    if (t + 1 < nK) stageA(bsel ^ 1, t + 1, 1);
    __builtin_amdgcn_s_barrier();
    __builtin_amdgcn_s_waitcnt(0xC07F);
    __builtin_amdgcn_sched_barrier(0);
    __builtin_amdgcn_s_setprio(1);
#pragma unroll
    for (int i = 0; i < 4; i++)
#pragma unroll
      for (int j = 0; j < 2; j++) {
        acc[i][2 + j] = __builtin_amdgcn_mfma_f32_16x16x32_bf16(a[i][0], b1[j][0], acc[i][2 + j], 0, 0, 0);
        acc[i][2 + j] = __builtin_amdgcn_mfma_f32_16x16x32_bf16(a[i][1], b1[j][1], acc[i][2 + j], 0, 0, 0);
      }
    __builtin_amdgcn_s_setprio(0);
    __builtin_amdgcn_s_barrier();

#pragma unroll
    for (int i = 0; i < IB_HI; i++) {
      a[i][0] = *(const bf16x8*)&S[arow + (4 + i) * 1024 + coff0];
      a[i][1] = *(const bf16x8*)&S[arow + (4 + i) * 1024 + coff1];
    }
    if (t + 2 < nK) stageB(bsel, t + 2, 0);
    __builtin_amdgcn_s_barrier();
    __builtin_amdgcn_s_waitcnt(0xC07F);
    __builtin_amdgcn_sched_barrier(0);
    __builtin_amdgcn_s_setprio(1);
#pragma unroll
    for (int i = 0; i < IB_HI; i++)
#pragma unroll
      for (int j = 0; j < 2; j++) {
        acc[4 + i][j] = __builtin_amdgcn_mfma_f32_16x16x32_bf16(a[i][0], b0[j][0], acc[4 + i][j], 0, 0, 0);
        acc[4 + i][j] = __builtin_amdgcn_mfma_f32_16x16x32_bf16(a[i][1], b0[j][1], acc[4 + i][j], 0, 0, 0);
      }
    __builtin_amdgcn_s_setprio(0);
    __builtin_amdgcn_s_barrier();

    if (t + 2 < nK) stageB(bsel, t + 2, 1);
    __builtin_amdgcn_s_barrier();
    __builtin_amdgcn_s_setprio(1);
#pragma unroll
    for (int i = 0; i < IB_HI; i++)
#pragma unroll
      for (int j = 0; j < 2; j++) {
        acc[4 + i][2 + j] = __builtin_amdgcn_mfma_f32_16x16x32_bf16(a[i][0], b1[j][0], acc[4 + i][2 + j], 0, 0, 0);
        acc[4 + i][2 + j] = __builtin_amdgcn_mfma_f32_16x16x32_bf16(a[i][1], b1[j][1], acc[4 + i][2 + j], 0, 0, 0);
      }
    __builtin_amdgcn_s_setprio(0);
    if (t + 2 < nK) __builtin_amdgcn_s_waitcnt(0xF74);
    else            __builtin_amdgcn_s_waitcnt(0xF70);
    __builtin_amdgcn_s_barrier();
  }

  float badd[4];
#pragma unroll
  for (int j = 0; j < 4; j++)
    badd[j] = bias[n0 + wn4 * 64 + j * 16 + l16];
#pragma unroll
  for (int i = 0; i < IB; i++) {
    const int mrow = m0 + wm2 * WMH + i * 16 + quad * 4;
#pragma unroll
    for (int j = 0; j < 4; j++) {
      const int n = n0 + wn4 * 64 + j * 16 + l16;
#pragma unroll
      for (int r = 0; r < 4; r++)
        C[(size_t)(mrow + r) * 1024 + n] = f2bf(acc[i][j][r] + badd[j]);
    }
  }
}

// ---------------- K3: LSTM step 1, TWO fragments per wave -----------------
// Both rows' loads issued before compute (2x MLP); zero-fills pad rows.
__global__ __launch_bounds__(256) void lstm_step1(
    const u16* __restrict__ P, const int* __restrict__ join,
    u16* __restrict__ h1, u16* __restrict__ c1) {
  int wave = threadIdx.x >> 6, lane = threadIdx.x & 63;
  int m0 = blockIdx.x * 8 + wave * 2;
  if (m0 >= N_FRAG_PAD) return;
#pragma unroll
  for (int c = 0; c < 2; ++c) {
    int m = m0 + c;
    if (m >= N_FRAG) {
      if (m < N_FRAG_PAD) {
        *(ushort4*)(h1 + (size_t)m * 256 + lane * 4) = make_ushort4(0, 0, 0, 0);
        *(ushort4*)(c1 + (size_t)m * 256 + lane * 4) = make_ushort4(0, 0, 0, 0);
      }
    }
  }
  if (m0 + 1 >= N_FRAG) return;   // tail handled above (wave-uniform)
  int j0a = join[2 * m0];
  int j0b = join[2 * (m0 + 1)];
  const u16* rowa = P + (size_t)j0a * 1024 + lane * 4;
  const u16* rowb = P + (size_t)j0b * 1024 + lane * 4;
  ushort4 iva = *(const ushort4*)(rowa);
  ushort4 gva = *(const ushort4*)(rowa + 512);
  ushort4 ova = *(const ushort4*)(rowa + 768);
  ushort4 ivb = *(const ushort4*)(rowb);
  ushort4 gvb = *(const ushort4*)(rowb + 512);
  ushort4 ovb = *(const ushort4*)(rowb + 768);
#pragma unroll
  for (int c = 0; c < 2; ++c) {
    const u16* ivp = (const u16*)(c ? &ivb : &iva);
    const u16* gvp = (const u16*)(c ? &gvb : &gva);
    const u16* ovp = (const u16*)(c ? &ovb : &ova);
    ushort4 h4, c4;
    u16* h4p = (u16*)&h4;
    u16* c4p = (u16*)&c4;
#pragma unroll
    for (int k = 0; k < 4; k++) {
      float cc = sigmoidf(bf2f(ivp[k])) * fast_tanh(bf2f(gvp[k]));
      float hv = sigmoidf(bf2f(ovp[k])) * fast_tanh(cc);
      h4p[k] = f2bf(hv);
      c4p[k] = f2bf(cc);
    }
    *(ushort4*)(h1 + (size_t)(m0 + c) * 256 + lane * 4) = h4;
    *(ushort4*)(c1 + (size_t)(m0 + c) * 256 + lane * 4) = c4;
  }
}

// ------- G2 fused: gates2 = h1 @ Whh^T (+P[j1], +c1) -> h2  ---------------
// 128x128 tile, BK=32, 256 thr, triple-buffered LDS (48 KiB, 3 blocks/CU).
// XCD-COLOCATED mapping (R8 verified): xcd = mstrip%8 so the 8 nstrip
// blocks of one mstrip share their XCD L2 for h1 tile + gathered P rows.
__global__ __launch_bounds__(256, 3) void g2fuse(
    const u16* __restrict__ h1A, const u16* __restrict__ Whhb,
    const u16* __restrict__ P, const int* __restrict__ join,
    const u16* __restrict__ c1in, u16* __restrict__ h2s) {
  constexpr int K = 256;
  __shared__ u16 sh[6][128 * 32];   // A bufs 0-2, B bufs 3-5 (48 KiB)
  const int b = blockIdx.x;
  const int xcd = b & 7;
  const int k = b >> 3;             // 0..631
  const int nstrip = k & 7;
  const int mstrip = (k >> 3) * 8 + xcd;   // 0..631
  if (mstrip >= 626) return;
  const int m0 = mstrip * 128;

  const int tid = threadIdx.x;
  const int lane = tid & 63;
  const int wave = tid >> 6;
  const int quad = lane >> 4;
  const int l16 = lane & 15;
  const int wm = (wave & 1) * 64;
  const int wnq = wave >> 1;        // 0..1
  const int wn = wnq * 64;

  int srow[2], skoff[2], ldsoff[2], brow[2];
#pragma unroll
  for (int jj = 0; jj < 2; jj++) {
    int c = jj * 256 + tid;
    int row = c >> 2;
    srow[jj] = row;
    skoff[jj] = ((c & 3) ^ ((c >> 3) & 3)) * 8;
    ldsoff[jj] = (jj * 256 + (tid & ~63)) * 8;
    brow[jj] = ((row >> 4) & 3) * 256 + nstrip * 32 + ((row >> 6) << 4) + (row & 15);
  }
  const u16* Abase = h1A + (size_t)m0 * K;

  int jrow[8];
#pragma unroll
  for (int rd = 0; rd < 8; rd++) {
    int mm = m0 + rd * 16 + (tid >> 4);
    jrow[rd] = join[2 * (mm < N_FRAG ? mm : N_FRAG - 1) + 1];
  }

  auto stage = [&](int buf, int k0) {
#pragma unroll
    for (int jj = 0; jj < 2; jj++)
      async_copy16(Abase + (size_t)srow[jj] * K + k0 + skoff[jj], &sh[buf][ldsoff[jj]]);
#pragma unroll
    for (int jj = 0; jj < 2; jj++)
      async_copy16(Whhb + (size_t)brow[jj] * K + k0 + skoff[jj], &sh[3 + buf][ldsoff[jj]]);
  };

  f32x4 acc[4][4];
#pragma unroll
  for (int i = 0; i < 4; i++)
#pragma unroll
    for (int j = 0; j < 4; j++) acc[i][j] = (f32x4){0.f, 0.f, 0.f, 0.f};

  constexpr int nK = K / 32;        // 8
  stage(0, 0);
  stage(1, 32);
#pragma unroll
  for (int t = 0; t < nK; ++t) {
    if (t < nK - 1) __builtin_amdgcn_s_waitcnt(0xF74);  // vmcnt(4)
    else            __builtin_amdgcn_s_waitcnt(0xF70);  // vmcnt(0)
    __builtin_amdgcn_s_barrier();
    if (t + 2 < nK) stage((t + 2) % 3, (t + 2) * 32);
    const int buf = t % 3;
    bf16x8 af[4], bfr[4];
#pragma unroll
    for (int i = 0; i < 4; i++) {
      int m = wm + i * 16 + l16;
      int jp = quad ^ ((m >> 1) & 3);
      af[i] = *(const bf16x8*)&sh[buf][m * 32 + jp * 8];
    }
#pragma unroll
    for (int j = 0; j < 4; j++) {
      int n = wn + j * 16 + l16;
      int jp = quad ^ ((n >> 1) & 3);
      bfr[j] = *(const bf16x8*)&sh[3 + buf][n * 32 + jp * 8];
    }
#pragma unroll
    for (int i = 0; i < 4; i++)
#pragma unroll
      for (int j = 0; j < 4; j++)
        acc[i][j] = __builtin_amdgcn_mfma_f32_16x16x32_bf16(af[i], bfr[j], acc[i][j], 0, 0, 0);
  }

  // ---- fused LSTM step-2 epilogue ----
  __builtin_amdgcn_s_barrier();
  const int u_ = wnq * 16 + l16;
  u16 c1r[4][4];
#pragma unroll
  for (int i = 0; i < 4; i++)
#pragma unroll
    for (int r = 0; r < 4; r++) {
      int m = m0 + wm + i * 16 + quad * 4 + r;
      c1r[i][r] = c1in[(size_t)m * 256 + nstrip * 32 + u_];
    }
  u16* Pl = &sh[0][0];              // 32 KiB
  {
    const int g = (tid >> 2) & 3;
    const int chunk = tid & 3;
#pragma unroll
    for (int rd = 0; rd < 8; rd++) {
      const int mloc = rd * 16 + (tid >> 4);
      const int cphys = chunk ^ ((mloc >> 2) & 3);
      async_copy16(P + (size_t)jrow[rd] * 1024 + g * 256 + nstrip * 32 + cphys * 8,
                   &Pl[(size_t)(rd * 256 + (tid & ~63)) * 8]);
    }
  }
  __builtin_amdgcn_s_waitcnt(0xF70);
  __builtin_amdgcn_s_barrier();
  __builtin_amdgcn_sched_barrier(0);

#pragma unroll
  for (int i = 0; i < 4; i++) {
#pragma unroll
    for (int r = 0; r < 4; r++) {
      const int mloc = wm + i * 16 + quad * 4 + r;
      const int m = m0 + mloc;
      const int base = (mloc * 16 + ((u_ >> 3) ^ ((mloc >> 2) & 3))) * 8 + (u_ & 7);
      float gi = acc[i][0][r] + bf2f(Pl[base]);
      float gf = acc[i][1][r] + bf2f(Pl[base + 32]);
      float gg = acc[i][2][r] + bf2f(Pl[base + 64]);
      float go = acc[i][3][r] + bf2f(Pl[base + 96]);
      float c1v = bf2f(c1r[i][r]);
      float cv = sigmoidf(gf) * c1v + sigmoidf(gi) * fast_tanh(gg);
      float hv = sigmoidf(go) * fast_tanh(cv);
      h2s[(size_t)m * 256 + nstrip * 32 + u_] = f2bf(hv);
    }
  }
}

// ------- K5: attention over {h1,h2} + output head, TWO frags per wave -----
__global__ __launch_bounds__(256) void lstm_attn_out(
    const u16* __restrict__ h1, const u16* __restrict__ h2s,
    const float* __restrict__ Wg, const float* __restrict__ Wout,
    const float* __restrict__ bout, float* __restrict__ frag_out) {
  int wave = threadIdx.x >> 6, lane = threadIdx.x & 63;
  int m0 = blockIdx.x * 8 + wave * 2;
  if (m0 >= N_FRAG) return;
  const int nf = (m0 + 1 < N_FRAG) ? 2 : 1;
  ushort4 h1v[2], h2v[2];
#pragma unroll
  for (int c = 0; c < 2; ++c) {
    int m = m0 + (c < nf ? c : 0);
    h1v[c] = *(const ushort4*)(h1 + (size_t)m * 256 + lane * 4);
    h2v[c] = *(const ushort4*)(h2s + (size_t)m * 256 + lane * 4);
  }
  float4 wg = *(const float4*)(Wg + lane * 4);
  const float* wgp = (const float*)&wg;

  float p1[2], p2[2];
#pragma unroll
  for (int c = 0; c < 2; ++c) {
    const u16* h1p = (const u16*)&h1v[c];
    const u16* h2p = (const u16*)&h2v[c];
    float a = 0.f, b = 0.f;
#pragma unroll
    for (int k = 0; k < 4; k++) {
      a += bf2f(h1p[k]) * wgp[k];
      b += bf2f(h2p[k]) * wgp[k];
    }
    p1[c] = a; p2[c] = b;
  }
#pragma unroll
  for (int off = 32; off; off >>= 1)
#pragma unroll
    for (int c = 0; c < 2; ++c) {
      p1[c] += __shfl_xor(p1[c], off);
      p2[c] += __shfl_xor(p2[c], off);
    }

  float acc[2][8];
#pragma unroll
  for (int c = 0; c < 2; ++c) {
    float mx = fmaxf(p1[c], p2[c]);
    float e1 = __expf(p1[c] - mx), e2 = __expf(p2[c] - mx);
    float inv = __frcp_rn(e1 + e2);
    float a1 = e1 * inv, a2 = e2 * inv;
    const u16* h1p = (const u16*)&h1v[c];
    const u16* h2p = (const u16*)&h2v[c];
#pragma unroll
    for (int t = 0; t < 8; t++) acc[c][t] = 0.f;
#pragma unroll
    for (int k = 0; k < 4; k++) {
      float frag = a1 * bf2f(h1p[k]) + a2 * bf2f(h2p[k]);
      int h = lane * 4 + k;
      float4 w0 = *(const float4*)(Wout + h * 8);
      float4 w1 = *(const float4*)(Wout + h * 8 + 4);
      acc[c][0] += frag * w0.x; acc[c][1] += frag * w0.y;
      acc[c][2] += frag * w0.z; acc[c][3] += frag * w0.w;
      acc[c][4] += frag * w1.x; acc[c][5] += frag * w1.y;
      acc[c][6] += frag * w1.z; acc[c][7] += frag * w1.w;
    }
  }
#pragma unroll
  for (int off = 32; off; off >>= 1)
#pragma unroll
    for (int c = 0; c < 2; ++c)
#pragma unroll
      for (int t = 0; t < 8; t++) acc[c][t] += __shfl_xor(acc[c][t], off);
  if (lane == 0) {
#pragma unroll
    for (int c = 0; c < 2; ++c) {
      if (c >= nf) break;
      float4 o0, o1;
      o0.x = fmaxf(acc[c][0] + bout[0], 0.f);
      o0.y = fmaxf(acc[c][1] + bout[1], 0.f);
      o0.z = fmaxf(acc[c][2] + bout[2], 0.f);
      o0.w = fmaxf(acc[c][3] + bout[3], 0.f);
      o1.x = fmaxf(acc[c][4] + bout[4], 0.f);
      o1.y = fmaxf(acc[c][5] + bout[5], 0.f);
      o1.z = fmaxf(acc[c][6] + bout[6], 0.f);
      o1.w = fmaxf(acc[c][7] + bout[7], 0.f);
      *(float4*)(frag_out + (size_t)(m0 + c) * 8) = o0;
      *(float4*)(frag_out + (size_t)(m0 + c) * 8 + 4) = o1;
    }
  }
}

// ---------------- K6: combine scatter-sum ---------------------------------
__global__ __launch_bounds__(256) void scatter_sum(
    const float* __restrict__ frag_out, const int* __restrict__ comb,
    float* __restrict__ out) {
  int tid = blockIdx.x * 256 + threadIdx.x;
  if (tid >= N_OUT * 8) return;
  int n = tid >> 3, t = tid & 7;
  float s = 0.f;
#pragma unroll
  for (int d = 0; d < 4; d++) {
    int f = comb[n * 4 + d];
    s += frag_out[(size_t)f * 8 + t];
  }
  out[tid] = s;
}

extern "C" void kernel_launch(void* const* d_in, const int* in_sizes, int n_in,
                              void* d_out, int out_size, void* d_ws, size_t ws_size,
                              hipStream_t stream) {
  const float* feature = (const float*)d_in[0];
  const float* WgL = (const float*)d_in[1];
  const float* WgR = (const float*)d_in[2];
  const float* Wih = (const float*)d_in[3];
  const float* Whh = (const float*)d_in[4];
  const float* bih = (const float*)d_in[5];
  const float* bhh = (const float*)d_in[6];
  const float* Wgf = (const float*)d_in[7];
  const float* Wout = (const float*)d_in[8];
  const float* bout = (const float*)d_in[9];
  const int* lostS = (const int*)d_in[10];
  const int* retS = (const int*)d_in[11];
  const int* joinS = (const int*)d_in[12];
  const int* combS = (const int*)d_in[13];
  float* out = (float*)d_out;

  char* ws = (char*)d_ws;
  size_t off = 0;
  auto alloc = [&](size_t bytes) -> char* {
    char* p = ws + off;
    off = (off + bytes + 255) & ~(size_t)255;
    return p;
  };
  u16* Wihb = (u16*)alloc((size_t)1024 * 512 * 2);
  u16* Whhb = (u16*)alloc((size_t)1024 * 256 * 2);
  float* bias = (float*)alloc(1024 * 4);
  u16* P = (u16*)alloc((size_t)M_CLEAV_PAD * 1024 * 2);
  u16* h1 = (u16*)alloc((size_t)N_FRAG_PAD * 256 * 2);
  u16* c1 = (u16*)alloc((size_t)N_FRAG_PAD * 256 * 2);
  u16* h2s = (u16*)alloc((size_t)N_FRAG_PAD * 256 * 2);
  float* frag_out = (float*)alloc((size_t)N_FRAG * 8 * 4);
  u16* cleav = (u16*)alloc((size_t)M_CLEAV_PAD * 512 * 2);
  // featb (76.8 MB) + glog (1.2 MB) alias the P region: dead once
  // attn_pull2 completes, before GEMM-1 writes P (stream-ordered).
  u16* featb = P;
  float* glog = (float*)(P + (size_t)N_MONO * F);

  prep_kernel<<<2048, 256, 0, stream>>>(Wih, Whh, bih, bhh, Wihb, Whhb, bias);
  feat_prep<<<(N_MONO + 3) / 4, 256, 0, stream>>>(feature, WgL, WgR, featb, glog);
  attn_pull2<<<N_CLEAV / 8, 256, 0, stream>>>(featb, glog, lostS, retS, cleav);
  // GEMM-1: M=100352 = 448*224 strips, 56/XCD, 1792 blocks = 7/CU exact
  gemm224<<<1792, 512, 0, stream>>>(cleav, Wihb, P, bias, 56, 448);
  lstm_step1<<<N_FRAG_PAD / 8, 256, 0, stream>>>(P, joinS, h1, c1);
  // G2 fused: 632 virtual mstrips (79/XCD) x 8 nstrips, XCD-colocated
  g2fuse<<<632 * 8, 256, 0, stream>>>(h1, Whhb, P, joinS, c1, h2s);
  lstm_attn_out<<<(N_FRAG + 7) / 8, 256, 0, stream>>>(
      h1, h2s, Wgf, Wout, bout, frag_out);
  scatter_sum<<<(N_OUT * 8 + 255) / 256, 256, 0, stream>>>(frag_out, combS, out);
}